// Round 16
// baseline (1246.681 us; speedup 1.0000x reference)
//
#include <hip/hip_runtime.h>

// ---- problem constants ----
#define kB 4
#define kV 2
#define kS 256
#define kW 32
#define kM 16
#define kNB 6
#define kTIN 10
#define kSTEP 5

#define NPLANE 65536            // S*S
#define NBWV   (kB*kW*kV)       // 256
#define BIGN   (kB*kW*kV*NPLANE)// 16777216 floats per state buffer
#define CHS    (kV*NPLANE)      // channel stride = 131072

// ---- workspace layout (float offsets) ----
#define OFF_BIG0 0
#define OFF_BIG1 16777216
#define OFF_BIG2 33554432
#define OFF_FYR  50331648   // [bwv][ky16][x256] = 1048576
#define OFF_FYI  51380224
#define OFF_FXR  52428800   // [bwv][ky16][j32] = 131072
#define OFF_FXI  52559872
#define OFF_GR   52690944
#define OFF_GI   52822016
#define OFF_TXC  52953088   // xdft fwd [x][j]  8192 (kept for reference)
#define OFF_TXS  52961280
#define OFF_TIC  52969472   // x inverse [j][x] 8192
#define OFF_TIS  52977664
#define OFF_IYC  52985856   // y inverse [k][y] 4096
#define OFF_IYS  52989952
#define OFF_WHI  52994048   // fc1 hi-bf16 frags [nt16][lane64][4 uints] = 4096
#define OFF_WLO  52998144   // fc1 lo-bf16 frags = 4096
#define OFF_YAH  53002240   // ydft table A-frags hi [mt2][kt8][lane64][4u] = 4096
#define OFF_YAL  53006336   // ydft table A-frags lo = 4096
#define OFF_XBH  53010432   // xdft table B-frags hi [tab3][jh2][kt8][l64][4u] = 12288
#define OFF_XBL  53022720   // xdft table B-frags lo = 12288
// total 53035008 floats ~= 202.3 MiB

typedef short bf16x8 __attribute__((ext_vector_type(8)));
typedef float f32x4 __attribute__((ext_vector_type(4)));

__device__ __forceinline__ unsigned short bf16_rne(float f){
    union { float f; unsigned int u; } x; x.f = f;
    unsigned int u = x.u + 0x7fffu + ((x.u>>16)&1u);
    return (unsigned short)(u>>16);
}
__device__ __forceinline__ float bf16_tof(unsigned short h){
    union { unsigned int u; float f; } x; x.u = ((unsigned int)h)<<16;
    return x.f;
}

// Fast exact-erf gelu: A&S 7.1.26, |erf err| <= 1.5e-7. Native rcp+exp.
__device__ __forceinline__ float gelu_f(float x){
    float z = fabsf(x) * 0.70710678118654752f;
    float t = __builtin_amdgcn_rcpf(1.0f + 0.3275911f*z);
    float poly = t*(0.254829592f + t*(-0.284496736f + t*(1.421413741f + t*(-1.453152027f + t*1.061405429f))));
    float e = __expf(-z*z);
    float erf_abs = 1.0f - poly*e;
    float ph = (x >= 0.0f) ? (1.0f + erf_abs) : (1.0f - erf_abs);
    return 0.5f * x * ph;
}

// ---- DFT tables + fc1 / ydft / xdft bf16 fragment packing ----
__global__ void k_tables(float* ws, const float* __restrict__ fc1w){
    const double PI = 3.14159265358979323846;
    int t = blockIdx.x*256 + threadIdx.x; // 8192 threads
    if (t < 8192){
        // forward x-DFT, [x][j]: e^{-i 2pi kx x /256} (reference tables)
        int x = t>>5, j = t&31;
        int kx = (j<16) ? j : (224+j);
        int p = (kx*x)&255;
        double a = (double)p*(PI/128.0);
        ws[OFF_TXC+t] = (float)cos(a);
        ws[OFF_TXS+t] = -(float)sin(a);
        // inverse x-DFT, [j][x]: e^{+i 2pi kx x /256}
        int j2 = t>>8, x2 = t&255;
        int kx2 = (j2<16) ? j2 : (224+j2);
        int p2 = (kx2*x2)&255;
        double a2 = (double)p2*(PI/128.0);
        ws[OFF_TIC+t] = (float)cos(a2);
        ws[OFF_TIS+t] = (float)sin(a2);
    }
    if (t < 4096){
        // y-irfft basis [k][y], scale 1/65536 folds both ifft normalizations
        int k = t>>8, y = t&255;
        int p = (k*y)&255;
        double a = (double)p*(PI/128.0);
        float sc = 1.0f/65536.0f;
        ws[OFF_IYC+t] = (k==0 ? 1.0f : 2.0f*(float)cos(a))*sc;
        ws[OFF_IYS+t] = (k==0 ? 0.0f : -2.0f*(float)sin(a))*sc;
    }
    if (t < 1024){
        // fc1 weight fragments for MFMA: tile nt, lane l:
        //   o = nt*16 + (l&15), channels c = (l>>4)*8 .. +7
        int nt = t>>6, l = t&63;
        int o = nt*16 + (l&15), c0 = (l>>4)*8;
        unsigned int hw[4], lw[4];
        #pragma unroll
        for (int e2=0; e2<4; e2++){
            float f0 = fc1w[(c0+2*e2  )*256 + o];
            float f1 = fc1w[(c0+2*e2+1)*256 + o];
            unsigned short h0 = bf16_rne(f0), h1 = bf16_rne(f1);
            unsigned short l0 = bf16_rne(f0 - bf16_tof(h0));
            unsigned short l1 = bf16_rne(f1 - bf16_tof(h1));
            hw[e2] = (unsigned int)h0 | ((unsigned int)h1<<16);
            lw[e2] = (unsigned int)l0 | ((unsigned int)l1<<16);
        }
        unsigned int* whi = (unsigned int*)(ws+OFF_WHI);
        unsigned int* wlo = (unsigned int*)(ws+OFF_WLO);
        #pragma unroll
        for (int e2=0; e2<4; e2++){
            whi[t*4+e2] = hw[e2];
            wlo[t*4+e2] = lw[e2];
        }
    }
    if (t < 1024){
        // ydft A-fragments: t = mt*512 + kt*64 + l
        //   mt=0: cos(2pi ky y/256); mt=1: -sin(...)
        //   lane l: m-row ky = l&15, k = kt*32 + (l>>4)*8 + e
        int mt = t>>9, kt = (t>>6)&7, l = t&63;
        int ky = l&15;
        unsigned int* yah = (unsigned int*)(ws+OFF_YAH);
        unsigned int* yal = (unsigned int*)(ws+OFF_YAL);
        #pragma unroll
        for (int e2=0; e2<4; e2++){
            int y0 = kt*32 + (l>>4)*8 + 2*e2;
            double a0 = (double)((ky*y0)&255)*(PI/128.0);
            double a1 = (double)((ky*(y0+1))&255)*(PI/128.0);
            float v0 = (mt==0) ? (float)cos(a0) : -(float)sin(a0);
            float v1 = (mt==0) ? (float)cos(a1) : -(float)sin(a1);
            unsigned short h0 = bf16_rne(v0), h1 = bf16_rne(v1);
            unsigned short s0 = bf16_rne(v0 - bf16_tof(h0));
            unsigned short s1 = bf16_rne(v1 - bf16_tof(h1));
            yah[t*4+e2] = (unsigned int)h0 | ((unsigned int)h1<<16);
            yal[t*4+e2] = (unsigned int)s0 | ((unsigned int)s1<<16);
        }
    }
    if (t < 3072){
        // xdft B-fragments: t = tab*1024 + jh*512 + kt*64 + l
        //   tab0: cos(2pi kx x/256); tab1: -sin; tab2: +sin
        //   lane l: n-col j = jh*16 + (l&15), k = x = kt*32 + (l>>4)*8 + e
        int tab = t>>10, jh = (t>>9)&1, kt = (t>>6)&7, l = t&63;
        int j = jh*16 + (l&15);
        int kx = (j<16) ? j : (224+j);
        unsigned int* xbh = (unsigned int*)(ws+OFF_XBH);
        unsigned int* xbl = (unsigned int*)(ws+OFF_XBL);
        #pragma unroll
        for (int e2=0; e2<4; e2++){
            int x0 = kt*32 + (l>>4)*8 + 2*e2;
            double a0 = (double)((kx*x0)&255)*(PI/128.0);
            double a1 = (double)((kx*(x0+1))&255)*(PI/128.0);
            float v0, v1;
            if (tab==0){ v0=(float)cos(a0); v1=(float)cos(a1); }
            else if (tab==1){ v0=-(float)sin(a0); v1=-(float)sin(a1); }
            else { v0=(float)sin(a0); v1=(float)sin(a1); }
            unsigned short h0 = bf16_rne(v0), h1 = bf16_rne(v1);
            unsigned short s0 = bf16_rne(v0 - bf16_tof(h0));
            unsigned short s1 = bf16_rne(v1 - bf16_tof(h1));
            xbh[t*4+e2] = (unsigned int)h0 | ((unsigned int)h1<<16);
            xbl[t*4+e2] = (unsigned int)s0 | ((unsigned int)s1<<16);
        }
    }
}

// ---- fc0 + grid concat + transpose to (B,W,V,S,S) ----
__global__ void k_fc0(const float* __restrict__ x, const float* __restrict__ w,
                      const float* __restrict__ bias, float* __restrict__ h0){
    int plane = blockIdx.x>>8, xr = blockIdx.x&255, y = threadIdx.x;
    int xy = xr*256+y;
    long p = (long)plane*NPLANE + xy;
    float f[12];
    #pragma unroll
    for (int i=0;i<10;i++) f[i]=x[p*10+i];
    f[10] = 9.5f + xr*(1.0f/255.0f);
    f[11] = -0.5f + y*(1.0f/255.0f);
    float acc[32];
    #pragma unroll
    for (int o=0;o<32;o++) acc[o]=bias[o];
    #pragma unroll
    for (int c=0;c<12;c++){
        float fv=f[c];
        #pragma unroll
        for (int o=0;o<32;o++) acc[o]+=fv*w[c*32+o];
    }
    int b=plane>>1, v=plane&1;
    int base = b*(kW*CHS) + v*NPLANE + xy;
    #pragma unroll
    for (int o=0;o<32;o++) h0[base + o*CHS]=acc[o];
}

// ---- forward y-DFT via MFMA: Fy[ky][x] = sum_y T[ky][y] h[x][y] ----
// grid: 512 blocks = (bwv256, half2); 512 threads = 8 waves; wave -> one x-tile
// Rolled kt-loop with loop-carried accs + in-loop operand loads: PROVEN SAFE
// (R13). Contrast: k_head-style bodies (fresh acc per iter + loop-invariant A)
// MUST be fully unrolled (R7/R8/R14 miscompile evidence).
__global__ __launch_bounds__(512) void k_ydft(const float* __restrict__ h,
        const unsigned int* __restrict__ yah, const unsigned int* __restrict__ yal,
        float* __restrict__ fyr, float* __restrict__ fyi){
    int bwv = blockIdx.x>>1, half = blockIdx.x&1;
    int tid = threadIdx.x;
    int wv = tid>>6, l = tid&63;
    int nt = half*8 + wv;
    int x = nt*16 + (l&15);
    int klo = (l>>4)*8;
    const float* hp = h + bwv*NPLANE + x*256 + klo;
    f32x4 accR = {0.f,0.f,0.f,0.f}, accI = {0.f,0.f,0.f,0.f};
    for (int kt=0; kt<8; ++kt){
        float4 b0 = *reinterpret_cast<const float4*>(hp + kt*32);
        float4 b1 = *reinterpret_cast<const float4*>(hp + kt*32 + 4);
        float bv[8] = {b0.x,b0.y,b0.z,b0.w,b1.x,b1.y,b1.z,b1.w};
        bf16x8 bh, bl;
        #pragma unroll
        for (int e=0;e<8;e++){
            unsigned short hb = bf16_rne(bv[e]);
            bh[e] = (short)hb;
            bl[e] = (short)bf16_rne(bv[e] - bf16_tof(hb));
        }
        uint4 a0h = *reinterpret_cast<const uint4*>(&yah[(kt*64+l)*4]);
        uint4 a0l = *reinterpret_cast<const uint4*>(&yal[(kt*64+l)*4]);
        uint4 a1h = *reinterpret_cast<const uint4*>(&yah[(512 + kt*64 + l)*4]);
        uint4 a1l = *reinterpret_cast<const uint4*>(&yal[(512 + kt*64 + l)*4]);
        bf16x8 AH0 = __builtin_bit_cast(bf16x8, a0h);
        bf16x8 AL0 = __builtin_bit_cast(bf16x8, a0l);
        bf16x8 AH1 = __builtin_bit_cast(bf16x8, a1h);
        bf16x8 AL1 = __builtin_bit_cast(bf16x8, a1l);
        accR = __builtin_amdgcn_mfma_f32_16x16x32_bf16(AH0, bh, accR, 0,0,0);
        accR = __builtin_amdgcn_mfma_f32_16x16x32_bf16(AH0, bl, accR, 0,0,0);
        accR = __builtin_amdgcn_mfma_f32_16x16x32_bf16(AL0, bh, accR, 0,0,0);
        accI = __builtin_amdgcn_mfma_f32_16x16x32_bf16(AH1, bh, accI, 0,0,0);
        accI = __builtin_amdgcn_mfma_f32_16x16x32_bf16(AH1, bl, accI, 0,0,0);
        accI = __builtin_amdgcn_mfma_f32_16x16x32_bf16(AL1, bh, accI, 0,0,0);
    }
    int ob = bwv*4096 + x;
    int ky0 = (l>>4)*4;
    #pragma unroll
    for (int r=0;r<4;r++){
        fyr[ob + (ky0+r)*256] = accR[r];
        fyi[ob + (ky0+r)*256] = accI[r];
    }
}

// ---- forward x-DFT via MFMA: Fx[ky][j] = sum_x Fy[ky][x] T[x][j] ----
// grid: 512 blocks = (bwv256, jh2) x 64 threads (1 wave).
__global__ __launch_bounds__(64) void k_xdft(const float* __restrict__ fyr,
        const float* __restrict__ fyi,
        const unsigned int* __restrict__ xbh, const unsigned int* __restrict__ xbl,
        float* __restrict__ fxr, float* __restrict__ fxi){
    int bwv = blockIdx.x>>1, jh = blockIdx.x&1;
    int l = threadIdx.x;
    int abase = bwv*4096 + (l&15)*256 + (l>>4)*8;
    const float* ar = fyr + abase;
    const float* ai = fyi + abase;
    f32x4 accR = {0.f,0.f,0.f,0.f}, accI = {0.f,0.f,0.f,0.f};
    for (int kt=0; kt<8; ++kt){
        float4 r0 = *reinterpret_cast<const float4*>(ar + kt*32);
        float4 r1 = *reinterpret_cast<const float4*>(ar + kt*32 + 4);
        float4 i0 = *reinterpret_cast<const float4*>(ai + kt*32);
        float4 i1 = *reinterpret_cast<const float4*>(ai + kt*32 + 4);
        float rv[8] = {r0.x,r0.y,r0.z,r0.w,r1.x,r1.y,r1.z,r1.w};
        float iv[8] = {i0.x,i0.y,i0.z,i0.w,i1.x,i1.y,i1.z,i1.w};
        bf16x8 Rh, Rl, Ih, Il;
        #pragma unroll
        for (int e=0;e<8;e++){
            unsigned short hb = bf16_rne(rv[e]);
            Rh[e] = (short)hb;
            Rl[e] = (short)bf16_rne(rv[e] - bf16_tof(hb));
            unsigned short hb2 = bf16_rne(iv[e]);
            Ih[e] = (short)hb2;
            Il[e] = (short)bf16_rne(iv[e] - bf16_tof(hb2));
        }
        int fb = (jh*512 + kt*64 + l)*4;       // tab stride = 1024 frags * 4
        uint4 ch = *reinterpret_cast<const uint4*>(&xbh[fb]);
        uint4 cl = *reinterpret_cast<const uint4*>(&xbl[fb]);
        uint4 sh = *reinterpret_cast<const uint4*>(&xbh[fb + 4096]);
        uint4 sl = *reinterpret_cast<const uint4*>(&xbl[fb + 4096]);
        uint4 ph = *reinterpret_cast<const uint4*>(&xbh[fb + 8192]);
        uint4 pl = *reinterpret_cast<const uint4*>(&xbl[fb + 8192]);
        bf16x8 CH = __builtin_bit_cast(bf16x8, ch);
        bf16x8 CL = __builtin_bit_cast(bf16x8, cl);
        bf16x8 SH = __builtin_bit_cast(bf16x8, sh);
        bf16x8 SL = __builtin_bit_cast(bf16x8, sl);
        bf16x8 PH = __builtin_bit_cast(bf16x8, ph);
        bf16x8 PL = __builtin_bit_cast(bf16x8, pl);
        // FxR = FyR*cos + FyI*sin
        accR = __builtin_amdgcn_mfma_f32_16x16x32_bf16(Rh, CH, accR, 0,0,0);
        accR = __builtin_amdgcn_mfma_f32_16x16x32_bf16(Rh, CL, accR, 0,0,0);
        accR = __builtin_amdgcn_mfma_f32_16x16x32_bf16(Rl, CH, accR, 0,0,0);
        accR = __builtin_amdgcn_mfma_f32_16x16x32_bf16(Ih, PH, accR, 0,0,0);
        accR = __builtin_amdgcn_mfma_f32_16x16x32_bf16(Ih, PL, accR, 0,0,0);
        accR = __builtin_amdgcn_mfma_f32_16x16x32_bf16(Il, PH, accR, 0,0,0);
        // FxI = FyR*(-sin) + FyI*cos
        accI = __builtin_amdgcn_mfma_f32_16x16x32_bf16(Rh, SH, accI, 0,0,0);
        accI = __builtin_amdgcn_mfma_f32_16x16x32_bf16(Rh, SL, accI, 0,0,0);
        accI = __builtin_amdgcn_mfma_f32_16x16x32_bf16(Rl, SH, accI, 0,0,0);
        accI = __builtin_amdgcn_mfma_f32_16x16x32_bf16(Ih, CH, accI, 0,0,0);
        accI = __builtin_amdgcn_mfma_f32_16x16x32_bf16(Ih, CL, accI, 0,0,0);
        accI = __builtin_amdgcn_mfma_f32_16x16x32_bf16(Il, CH, accI, 0,0,0);
    }
    int ob = bwv*512 + jh*16 + (l&15);
    int ky0 = (l>>4)*4;
    #pragma unroll
    for (int r=0;r<4;r++){
        fxr[ob + (ky0+r)*32] = accR[r];
        fxi[ob + (ky0+r)*32] = accI[r];
    }
}

// ---- complex mode mixing (w1/w2) with mlp1 fused via LDS ----
// grid: 256 blocks = (b4, v2, ky16, jh2); 512 threads = (o32, j16)
__global__ void k_modemix(const float* __restrict__ fxr, const float* __restrict__ fxi,
                          const float* __restrict__ w1r_, const float* __restrict__ w1i_,
                          const float* __restrict__ w2r_, const float* __restrict__ w2i_,
                          const float* __restrict__ m1, float* __restrict__ g2r, float* __restrict__ g2i){
    __shared__ float glr[32*17], gli[32*17];
    int blk = blockIdx.x;
    int jh = blk&1, ky = (blk>>1)&15, v = (blk>>5)&1, b = blk>>6;
    int o = threadIdx.x>>4, jl = threadIdx.x&15;
    int j = jh*16 + jl;
    int kxi = (j<16) ? j : (j-16);
    const float* wr_ = (j<16) ? w1r_ : w2r_;
    const float* wi_ = (j<16) ? w1i_ : w2i_;
    int wbase = (o*kV + v)*256 + kxi*16 + ky;         // + i*16384
    int fbase = (b*kW*kV + v)*512 + ky*32 + j;        // + i*1024
    float re=0.f, im=0.f;
    #pragma unroll 8
    for (int i=0;i<32;i++){
        float fr=fxr[fbase+i*1024], fi=fxi[fbase+i*1024];
        float wr=wr_[wbase+i*16384], wi=wi_[wbase+i*16384];
        re += fr*wr - fi*wi;
        im += fr*wi + fi*wr;
    }
    glr[o*17+jl]=re; gli[o*17+jl]=im;
    __syncthreads();
    // mlp1: g2[o] = sum_i m1[o][i] * g[i]   (same-j mixing only)
    float r2=0.f, i2=0.f;
    #pragma unroll 8
    for (int i=0;i<32;i++){
        float m = m1[o*32+i];
        r2 += m*glr[i*17+jl];
        i2 += m*gli[i*17+jl];
    }
    int gid = ((b*kW + o)*kV + v)*512 + ky*32 + j;
    g2r[gid]=r2; g2i[gid]=i2;
}

// ---- FUSED inverse + pointwise: x-iDFT + y-irfft + mlp1b + gelu (t in LDS)
//      then mlp2(t) + ww*h + grid-term + gelu + residual.
// grid: 2048 blocks = (b4, v2, xr256); 256 threads. Kills the 128MB t round-trip.
__global__ void k_invpoint(const float* __restrict__ g2r, const float* __restrict__ g2i,
                           const float* __restrict__ xic, const float* __restrict__ xis,
                           const float* __restrict__ iyc, const float* __restrict__ iys,
                           const float* __restrict__ b1,
                           const float* h, const float* res, float* out,
                           const float* __restrict__ m2, const float* __restrict__ b2,
                           const float* __restrict__ ww_, const float* __restrict__ wb_,
                           const float* __restrict__ bw_, const float* __restrict__ bb_){
    __shared__ float frl[16*36], fil[16*36];   // [k][o] pad 36: b128 reads conflict-free
    __shared__ float tl[32*260];               // [c][y] pad 260: ph2b reads 2-lane/bank
    int tid = threadIdx.x;
    int blk = blockIdx.x;
    int b = blk>>9, v = (blk>>8)&1, xr = blk&255;

    // ---- phase 1: x-iDFT at fixed x=xr: F[o][k] = sum_j g2[o][k][j]*e^{+i th} ----
    #pragma unroll
    for (int pp=0; pp<2; pp++){
        int p = tid + pp*256;
        int o = p>>4, k = p&15;
        const float* gr_ = g2r + (((b*kW + o)*kV + v)<<9) + k*32;
        const float* gi_ = g2i + (((b*kW + o)*kV + v)<<9) + k*32;
        float re=0.f, im=0.f;
        #pragma unroll 8
        for (int j=0;j<32;j++){
            float grv=gr_[j], giv=gi_[j];
            float c=xic[j*256+xr], s=xis[j*256+xr];   // wave-uniform table reads
            re += grv*c - giv*s;
            im += grv*s + giv*c;
        }
        frl[k*36+o]=re; fil[k*36+o]=im;
    }
    __syncthreads();

    // ---- phase 2a: y-irfft, 4o x 8y tile per thread; t = gelu(acc + b1) ----
    {
        int og = tid&7, yg = tid>>3;
        int o0 = og*4, y0 = yg*8;
        float acc[4][8];
        #pragma unroll
        for (int oo=0;oo<4;oo++){
            float bb1 = b1[o0+oo];
            #pragma unroll
            for (int yy=0;yy<8;yy++) acc[oo][yy]=bb1;
        }
        #pragma unroll 4
        for (int k=0;k<16;k++){
            float4 yc0 = *reinterpret_cast<const float4*>(&iyc[k*256+y0]);
            float4 yc1 = *reinterpret_cast<const float4*>(&iyc[k*256+y0+4]);
            float4 ys0 = *reinterpret_cast<const float4*>(&iys[k*256+y0]);
            float4 ys1 = *reinterpret_cast<const float4*>(&iys[k*256+y0+4]);
            float4 fr4 = *reinterpret_cast<const float4*>(&frl[k*36+o0]);
            float4 fi4 = *reinterpret_cast<const float4*>(&fil[k*36+o0]);
            float frv[4]={fr4.x,fr4.y,fr4.z,fr4.w};
            float fiv[4]={fi4.x,fi4.y,fi4.z,fi4.w};
            #pragma unroll
            for (int oo=0;oo<4;oo++){
                acc[oo][0] += frv[oo]*yc0.x + fiv[oo]*ys0.x;
                acc[oo][1] += frv[oo]*yc0.y + fiv[oo]*ys0.y;
                acc[oo][2] += frv[oo]*yc0.z + fiv[oo]*ys0.z;
                acc[oo][3] += frv[oo]*yc0.w + fiv[oo]*ys0.w;
                acc[oo][4] += frv[oo]*yc1.x + fiv[oo]*ys1.x;
                acc[oo][5] += frv[oo]*yc1.y + fiv[oo]*ys1.y;
                acc[oo][6] += frv[oo]*yc1.z + fiv[oo]*ys1.z;
                acc[oo][7] += frv[oo]*yc1.w + fiv[oo]*ys1.w;
            }
        }
        #pragma unroll
        for (int oo=0;oo<4;oo++){
            float4 w0, w1;
            w0.x = gelu_f(acc[oo][0]); w0.y = gelu_f(acc[oo][1]);
            w0.z = gelu_f(acc[oo][2]); w0.w = gelu_f(acc[oo][3]);
            w1.x = gelu_f(acc[oo][4]); w1.y = gelu_f(acc[oo][5]);
            w1.z = gelu_f(acc[oo][6]); w1.w = gelu_f(acc[oo][7]);
            *reinterpret_cast<float4*>(&tl[(o0+oo)*260 + y0])   = w0;
            *reinterpret_cast<float4*>(&tl[(o0+oo)*260 + y0+4]) = w1;
        }
    }
    __syncthreads();

    // ---- phase 2b: pointmix (identical math to old k_pointmix) ----
    int y = tid;
    int pbase = b*(kW*CHS) + v*NPLANE + xr*256 + y;
    float gx = 9.5f + xr*(1.0f/255.0f);
    float gy = -0.5f + y*(1.0f/255.0f);
    float tv[32], hv[32];
    #pragma unroll
    for (int c=0;c<32;c++) tv[c]=tl[c*260+y];
    #pragma unroll
    for (int c=0;c<32;c++) hv[c]=h[pbase + c*CHS];
    #pragma unroll 4
    for (int o=0;o<32;o++){
        float s = b2[o]+wb_[o]+bb_[o] + bw_[o*2]*gx + bw_[o*2+1]*gy;
        #pragma unroll
        for (int c=0;c<32;c++) s += tv[c]*m2[o*32+c];
        #pragma unroll
        for (int c=0;c<32;c++) s += hv[c]*ww_[o*32+c];
        float r = gelu_f(s);
        if (res) r += res[pbase+o*CHS];
        out[pbase+o*CHS] = r;
    }
}

// ---- head via MFMA: 8 waves, nt split across wave pairs; LDS partial combine.
// RULE (3x confirmed: R7/R8/R14 all absmax~4.5e-2): MFMA bodies with fresh acc
// + loop-invariant A-frags must be FULLY unrolled with constant bounds.
// Here each wave fully unrolls 8 nt (16 uint4 weights hoisted, vs 32 before)
// to cut VGPR and raise occupancy; the o-sum (fc2) is associative so the two
// nt-halves combine through LDS.
__global__ __launch_bounds__(512) void k_head(const float* __restrict__ h,
        const unsigned int* __restrict__ whi, const unsigned int* __restrict__ wlo,
        const float* __restrict__ fc1b, const float* __restrict__ fc2w,
        const float* __restrict__ fc2b, float* __restrict__ out){
    __shared__ float hl[32*257];   // pad 257: 2-way bank overlap = free
    __shared__ float part[8*4*4*5]; // [wave][lg][r][j] partial fj
    int tid = threadIdx.x;
    int plane = blockIdx.x>>8, xr = blockIdx.x&255;
    int b = plane>>1, v = plane&1;
    const float* hp = h + b*(kW*CHS) + v*NPLANE + xr*256;
    for (int l2=tid; l2<8192; l2+=512)
        hl[(l2>>8)*257 + (l2&255)] = hp[(l2>>8)*CHS + (l2&255)];
    __syncthreads();

    int w = tid>>6, l = tid&63;
    int q = w>>1, hn = w&1;          // pixel quarter, nt half
    int lm = l&15, lg = l>>4;
    float f2b[5];
    #pragma unroll
    for (int j=0;j<5;j++) f2b[j] = fc2b[j];

    for (int mt=0; mt<4; ++mt){
        int pxl = q*64 + mt*16 + lm;
        bf16x8 ah, al;
        #pragma unroll
        for (int e=0;e<8;e++){
            float a = hl[(lg*8+e)*257 + pxl];
            unsigned short hb = bf16_rne(a);
            ah[e] = (short)hb;
            al[e] = (short)bf16_rne(a - bf16_tof(hb));
        }
        float fj[4][5];
        #pragma unroll
        for (int r=0;r<4;r++)
            #pragma unroll
            for (int j=0;j<5;j++) fj[r][j]=0.f;
        #pragma unroll
        for (int ntq=0; ntq<8; ntq++){
            int nt = hn*8 + ntq;
            uint4 rh = *reinterpret_cast<const uint4*>(&whi[(nt*64+l)*4]);
            uint4 rl = *reinterpret_cast<const uint4*>(&wlo[(nt*64+l)*4]);
            bf16x8 BH = __builtin_bit_cast(bf16x8, rh);
            bf16x8 BL = __builtin_bit_cast(bf16x8, rl);
            f32x4 d = {0.f,0.f,0.f,0.f};
            d = __builtin_amdgcn_mfma_f32_16x16x32_bf16(ah, BH, d, 0,0,0);
            d = __builtin_amdgcn_mfma_f32_16x16x32_bf16(ah, BL, d, 0,0,0);
            d = __builtin_amdgcn_mfma_f32_16x16x32_bf16(al, BH, d, 0,0,0);
            int o = nt*16 + lm;
            float b1  = fc1b[o];
            float w20 = fc2w[o*5+0], w21 = fc2w[o*5+1], w22 = fc2w[o*5+2];
            float w23 = fc2w[o*5+3], w24 = fc2w[o*5+4];
            #pragma unroll
            for (int r=0;r<4;r++){
                float u = gelu_f(d[r] + b1);
                fj[r][0] += u*w20; fj[r][1] += u*w21; fj[r][2] += u*w22;
                fj[r][3] += u*w23; fj[r][4] += u*w24;
            }
        }
        // reduce over the 16 o-lanes (lm bits)
        #pragma unroll
        for (int m=1; m<16; m<<=1){
            #pragma unroll
            for (int r=0;r<4;r++){
                #pragma unroll
                for (int j=0;j<5;j++) fj[r][j] += __shfl_xor(fj[r][j], m, 64);
            }
        }
        if (lm == 0){
            #pragma unroll
            for (int r=0;r<4;r++)
                #pragma unroll
                for (int j=0;j<5;j++) part[((w*4+lg)*4+r)*5+j] = fj[r][j];
        }
        __syncthreads();
        if (hn == 0 && lm == 0){
            int prow = blockIdx.x*256 + q*64 + mt*16 + lg*4;
            #pragma unroll
            for (int r=0;r<4;r++){
                long ob = (long)(prow+r)*5;
                #pragma unroll
                for (int j=0;j<5;j++)
                    out[ob+j] = fj[r][j] + part[(((w^1)*4+lg)*4+r)*5+j] + f2b[j];
            }
        }
        __syncthreads();
    }
}

extern "C" void kernel_launch(void* const* d_in, const int* in_sizes, int n_in,
                              void* d_out, int out_size, void* d_ws, size_t ws_size,
                              hipStream_t stream){
    const float* x    =(const float*)d_in[0];
    const float* fc0w =(const float*)d_in[1];
    const float* fc0b =(const float*)d_in[2];
    const float* w1r  =(const float*)d_in[3];
    const float* w1i  =(const float*)d_in[4];
    const float* w2r  =(const float*)d_in[5];
    const float* w2i  =(const float*)d_in[6];
    const float* m1w  =(const float*)d_in[7];
    const float* m1b  =(const float*)d_in[8];
    const float* m2w  =(const float*)d_in[9];
    const float* m2b  =(const float*)d_in[10];
    const float* ww   =(const float*)d_in[11];
    const float* wb   =(const float*)d_in[12];
    const float* bw   =(const float*)d_in[13];
    const float* bb   =(const float*)d_in[14];
    const float* fc1w =(const float*)d_in[15];
    const float* fc1b =(const float*)d_in[16];
    const float* fc2w =(const float*)d_in[17];
    const float* fc2b =(const float*)d_in[18];

    float* ws = (float*)d_ws;
    float* big[3] = {ws+OFF_BIG0, ws+OFF_BIG1, ws+OFF_BIG2};
    float* fyr = ws+OFF_FYR; float* fyi = ws+OFF_FYI;
    float* fxr = ws+OFF_FXR; float* fxi = ws+OFF_FXI;
    float* gr  = ws+OFF_GR;  float* gi  = ws+OFF_GI;

    k_tables<<<32,256,0,stream>>>(ws, fc1w);
    k_fc0<<<2048,256,0,stream>>>(x, fc0w, fc0b, big[0]);

    // schedule: {in, out, res}
    const int s_in [6] = {0,0,2,2,2,0};
    const int s_out[6] = {0,2,2,2,0,0};
    const int s_res[6] = {-1,-1,0,-1,-1,2};

    for (int blk=0; blk<6; ++blk){
        float* in   = big[s_in[blk]];
        float* outb = big[s_out[blk]];
        const float* resp = (s_res[blk] < 0) ? nullptr : big[s_res[blk]];
        k_ydft<<<512,512,0,stream>>>(in,
            (const unsigned int*)(ws+OFF_YAH), (const unsigned int*)(ws+OFF_YAL),
            fyr, fyi);
        k_xdft<<<512,64,0,stream>>>(fyr, fyi,
            (const unsigned int*)(ws+OFF_XBH), (const unsigned int*)(ws+OFF_XBL),
            fxr, fxi);
        k_modemix<<<256,512,0,stream>>>(fxr, fxi,
            w1r+blk*524288, w1i+blk*524288, w2r+blk*524288, w2i+blk*524288,
            m1w+blk*1024, gr, gi);
        k_invpoint<<<2048,256,0,stream>>>(gr, gi, ws+OFF_TIC, ws+OFF_TIS,
            ws+OFF_IYC, ws+OFF_IYS, m1b+blk*32,
            in, resp, outb,
            m2w+blk*1024, m2b+blk*32, ww+blk*1024, wb+blk*32, bw+blk*64, bb+blk*32);
    }
    k_head<<<2048,512,0,stream>>>(big[0],
        (const unsigned int*)(ws+OFF_WHI), (const unsigned int*)(ws+OFF_WLO),
        fc1b, fc2w, fc2b, (float*)d_out);
}

// Round 17
// 1233.521 us; speedup vs baseline: 1.0107x; 1.0107x over previous
//
#include <hip/hip_runtime.h>

// ---- problem constants ----
#define kB 4
#define kV 2
#define kS 256
#define kW 32
#define kM 16
#define kNB 6
#define kTIN 10
#define kSTEP 5

#define NPLANE 65536            // S*S
#define NBWV   (kB*kW*kV)       // 256
#define BIGN   (kB*kW*kV*NPLANE)// 16777216 floats per state buffer
#define CHS    (kV*NPLANE)      // channel stride = 131072

// ---- workspace layout (float offsets) ----
#define OFF_BIG0 0
#define OFF_BIG1 16777216
#define OFF_BIG2 33554432
#define OFF_FXR  52428800   // [bwv][ky16][j32] = 131072
#define OFF_FXI  52559872
#define OFF_GR   52690944
#define OFF_GI   52822016
#define OFF_TIC  52969472   // x inverse [j][x] 8192
#define OFF_TIS  52977664
#define OFF_IYC  52985856   // y inverse [k][y] 4096
#define OFF_IYS  52989952
#define OFF_WHI  52994048   // fc1 hi-bf16 frags [nt16][lane64][4 uints] = 4096
#define OFF_WLO  52998144   // fc1 lo-bf16 frags = 4096
#define OFF_YAH  53002240   // ydft table A-frags hi [mt2][kt8][lane64][4u] = 4096
#define OFF_YAL  53006336   // ydft table A-frags lo = 4096
#define OFF_XBH  53010432   // xdft table B-frags hi [tab3][jh2][kt8][l64][4u] = 12288
#define OFF_XBL  53022720   // xdft table B-frags lo = 12288
// total 53035008 floats ~= 202.3 MiB

typedef short bf16x8 __attribute__((ext_vector_type(8)));
typedef float f32x4 __attribute__((ext_vector_type(4)));

__device__ __forceinline__ unsigned short bf16_rne(float f){
    union { float f; unsigned int u; } x; x.f = f;
    unsigned int u = x.u + 0x7fffu + ((x.u>>16)&1u);
    return (unsigned short)(u>>16);
}
__device__ __forceinline__ float bf16_tof(unsigned short h){
    union { unsigned int u; float f; } x; x.u = ((unsigned int)h)<<16;
    return x.f;
}

// Fast exact-erf gelu: A&S 7.1.26, |erf err| <= 1.5e-7. Native rcp+exp.
__device__ __forceinline__ float gelu_f(float x){
    float z = fabsf(x) * 0.70710678118654752f;
    float t = __builtin_amdgcn_rcpf(1.0f + 0.3275911f*z);
    float poly = t*(0.254829592f + t*(-0.284496736f + t*(1.421413741f + t*(-1.453152027f + t*1.061405429f))));
    float e = __expf(-z*z);
    float erf_abs = 1.0f - poly*e;
    float ph = (x >= 0.0f) ? (1.0f + erf_abs) : (1.0f - erf_abs);
    return 0.5f * x * ph;
}

// ---- DFT tables + fc1 / ydft / xdft bf16 fragment packing ----
__global__ void k_tables(float* ws, const float* __restrict__ fc1w){
    const double PI = 3.14159265358979323846;
    int t = blockIdx.x*256 + threadIdx.x; // 8192 threads
    if (t < 8192){
        // inverse x-DFT, [j][x]: e^{+i 2pi kx x /256}
        int j2 = t>>8, x2 = t&255;
        int kx2 = (j2<16) ? j2 : (224+j2);
        int p2 = (kx2*x2)&255;
        double a2 = (double)p2*(PI/128.0);
        ws[OFF_TIC+t] = (float)cos(a2);
        ws[OFF_TIS+t] = (float)sin(a2);
    }
    if (t < 4096){
        // y-irfft basis [k][y], scale 1/65536 folds both ifft normalizations
        int k = t>>8, y = t&255;
        int p = (k*y)&255;
        double a = (double)p*(PI/128.0);
        float sc = 1.0f/65536.0f;
        ws[OFF_IYC+t] = (k==0 ? 1.0f : 2.0f*(float)cos(a))*sc;
        ws[OFF_IYS+t] = (k==0 ? 0.0f : -2.0f*(float)sin(a))*sc;
    }
    if (t < 1024){
        // fc1 weight fragments for MFMA: tile nt, lane l:
        //   o = nt*16 + (l&15), channels c = (l>>4)*8 .. +7
        int nt = t>>6, l = t&63;
        int o = nt*16 + (l&15), c0 = (l>>4)*8;
        unsigned int hw[4], lw[4];
        #pragma unroll
        for (int e2=0; e2<4; e2++){
            float f0 = fc1w[(c0+2*e2  )*256 + o];
            float f1 = fc1w[(c0+2*e2+1)*256 + o];
            unsigned short h0 = bf16_rne(f0), h1 = bf16_rne(f1);
            unsigned short l0 = bf16_rne(f0 - bf16_tof(h0));
            unsigned short l1 = bf16_rne(f1 - bf16_tof(h1));
            hw[e2] = (unsigned int)h0 | ((unsigned int)h1<<16);
            lw[e2] = (unsigned int)l0 | ((unsigned int)l1<<16);
        }
        unsigned int* whi = (unsigned int*)(ws+OFF_WHI);
        unsigned int* wlo = (unsigned int*)(ws+OFF_WLO);
        #pragma unroll
        for (int e2=0; e2<4; e2++){
            whi[t*4+e2] = hw[e2];
            wlo[t*4+e2] = lw[e2];
        }
    }
    if (t < 1024){
        // ydft A-fragments: t = mt*512 + kt*64 + l
        //   mt=0: cos(2pi ky y/256); mt=1: -sin(...)
        //   lane l: m-row ky = l&15, k = kt*32 + (l>>4)*8 + e
        int mt = t>>9, kt = (t>>6)&7, l = t&63;
        int ky = l&15;
        unsigned int* yah = (unsigned int*)(ws+OFF_YAH);
        unsigned int* yal = (unsigned int*)(ws+OFF_YAL);
        #pragma unroll
        for (int e2=0; e2<4; e2++){
            int y0 = kt*32 + (l>>4)*8 + 2*e2;
            double a0 = (double)((ky*y0)&255)*(PI/128.0);
            double a1 = (double)((ky*(y0+1))&255)*(PI/128.0);
            float v0 = (mt==0) ? (float)cos(a0) : -(float)sin(a0);
            float v1 = (mt==0) ? (float)cos(a1) : -(float)sin(a1);
            unsigned short h0 = bf16_rne(v0), h1 = bf16_rne(v1);
            unsigned short s0 = bf16_rne(v0 - bf16_tof(h0));
            unsigned short s1 = bf16_rne(v1 - bf16_tof(h1));
            yah[t*4+e2] = (unsigned int)h0 | ((unsigned int)h1<<16);
            yal[t*4+e2] = (unsigned int)s0 | ((unsigned int)s1<<16);
        }
    }
    if (t < 3072){
        // xdft B-fragments: t = tab*1024 + jh*512 + kt*64 + l
        //   tab0: cos(2pi kx x/256); tab1: -sin; tab2: +sin
        //   lane l: n-col j = jh*16 + (l&15), k = x = kt*32 + (l>>4)*8 + e
        int tab = t>>10, jh = (t>>9)&1, kt = (t>>6)&7, l = t&63;
        int j = jh*16 + (l&15);
        int kx = (j<16) ? j : (224+j);
        unsigned int* xbh = (unsigned int*)(ws+OFF_XBH);
        unsigned int* xbl = (unsigned int*)(ws+OFF_XBL);
        #pragma unroll
        for (int e2=0; e2<4; e2++){
            int x0 = kt*32 + (l>>4)*8 + 2*e2;
            double a0 = (double)((kx*x0)&255)*(PI/128.0);
            double a1 = (double)((kx*(x0+1))&255)*(PI/128.0);
            float v0, v1;
            if (tab==0){ v0=(float)cos(a0); v1=(float)cos(a1); }
            else if (tab==1){ v0=-(float)sin(a0); v1=-(float)sin(a1); }
            else { v0=(float)sin(a0); v1=(float)sin(a1); }
            unsigned short h0 = bf16_rne(v0), h1 = bf16_rne(v1);
            unsigned short s0 = bf16_rne(v0 - bf16_tof(h0));
            unsigned short s1 = bf16_rne(v1 - bf16_tof(h1));
            xbh[t*4+e2] = (unsigned int)h0 | ((unsigned int)h1<<16);
            xbl[t*4+e2] = (unsigned int)s0 | ((unsigned int)s1<<16);
        }
    }
}

// ---- fc0 + grid concat + transpose to (B,W,V,S,S) ----
__global__ void k_fc0(const float* __restrict__ x, const float* __restrict__ w,
                      const float* __restrict__ bias, float* __restrict__ h0){
    int plane = blockIdx.x>>8, xr = blockIdx.x&255, y = threadIdx.x;
    int xy = xr*256+y;
    long p = (long)plane*NPLANE + xy;
    float f[12];
    #pragma unroll
    for (int i=0;i<10;i++) f[i]=x[p*10+i];
    f[10] = 9.5f + xr*(1.0f/255.0f);
    f[11] = -0.5f + y*(1.0f/255.0f);
    float acc[32];
    #pragma unroll
    for (int o=0;o<32;o++) acc[o]=bias[o];
    #pragma unroll
    for (int c=0;c<12;c++){
        float fv=f[c];
        #pragma unroll
        for (int o=0;o<32;o++) acc[o]+=fv*w[c*32+o];
    }
    int b=plane>>1, v=plane&1;
    int base = b*(kW*CHS) + v*NPLANE + xy;
    #pragma unroll
    for (int o=0;o<32;o++) h0[base + o*CHS]=acc[o];
}

// ---- FUSED forward FFT: ydft (MFMA) -> LDS -> xdft (MFMA) ----
// grid: 256 blocks = bwv; 512 threads = 8 waves.
// Phase 1: each wave does 2 x-tiles of Fy[ky][x] = sum_y T[ky][y] h[x][y],
// storing to padded LDS (pad 260: writes 2-way/free, b128 reads <=4-way).
// Phase 2: waves 0-1 compute Fx[ky][j] = sum_x Fy[ky][x] T[x][j] from LDS.
// Loop shapes: plain constant-bound outer loop + rolled kt-loop with
// loop-carried accs (both HW-validated; see k_head rule for the unsafe form).
__global__ __launch_bounds__(512) void k_fwdfft(const float* __restrict__ h,
        const unsigned int* __restrict__ yah, const unsigned int* __restrict__ yal,
        const unsigned int* __restrict__ xbh, const unsigned int* __restrict__ xbl,
        float* __restrict__ fxr, float* __restrict__ fxi){
    __shared__ float fyrl[16*260], fyil[16*260];
    int bwv = blockIdx.x;
    int tid = threadIdx.x;
    int wv = tid>>6, l = tid&63;

    for (int half=0; half<2; ++half){
        int nt = wv*2 + half;            // 0..15
        int x = nt*16 + (l&15);
        int klo = (l>>4)*8;
        const float* hp = h + bwv*NPLANE + x*256 + klo;
        f32x4 accR = {0.f,0.f,0.f,0.f}, accI = {0.f,0.f,0.f,0.f};
        for (int kt=0; kt<8; ++kt){
            float4 b0 = *reinterpret_cast<const float4*>(hp + kt*32);
            float4 b1 = *reinterpret_cast<const float4*>(hp + kt*32 + 4);
            float bv[8] = {b0.x,b0.y,b0.z,b0.w,b1.x,b1.y,b1.z,b1.w};
            bf16x8 bh, bl;
            #pragma unroll
            for (int e=0;e<8;e++){
                unsigned short hb = bf16_rne(bv[e]);
                bh[e] = (short)hb;
                bl[e] = (short)bf16_rne(bv[e] - bf16_tof(hb));
            }
            uint4 a0h = *reinterpret_cast<const uint4*>(&yah[(kt*64+l)*4]);
            uint4 a0l = *reinterpret_cast<const uint4*>(&yal[(kt*64+l)*4]);
            uint4 a1h = *reinterpret_cast<const uint4*>(&yah[(512 + kt*64 + l)*4]);
            uint4 a1l = *reinterpret_cast<const uint4*>(&yal[(512 + kt*64 + l)*4]);
            bf16x8 AH0 = __builtin_bit_cast(bf16x8, a0h);
            bf16x8 AL0 = __builtin_bit_cast(bf16x8, a0l);
            bf16x8 AH1 = __builtin_bit_cast(bf16x8, a1h);
            bf16x8 AL1 = __builtin_bit_cast(bf16x8, a1l);
            accR = __builtin_amdgcn_mfma_f32_16x16x32_bf16(AH0, bh, accR, 0,0,0);
            accR = __builtin_amdgcn_mfma_f32_16x16x32_bf16(AH0, bl, accR, 0,0,0);
            accR = __builtin_amdgcn_mfma_f32_16x16x32_bf16(AL0, bh, accR, 0,0,0);
            accI = __builtin_amdgcn_mfma_f32_16x16x32_bf16(AH1, bh, accI, 0,0,0);
            accI = __builtin_amdgcn_mfma_f32_16x16x32_bf16(AH1, bl, accI, 0,0,0);
            accI = __builtin_amdgcn_mfma_f32_16x16x32_bf16(AL1, bh, accI, 0,0,0);
        }
        int ky0 = (l>>4)*4;
        #pragma unroll
        for (int r=0;r<4;r++){
            fyrl[(ky0+r)*260 + x] = accR[r];
            fyil[(ky0+r)*260 + x] = accI[r];
        }
    }
    __syncthreads();

    if (wv < 2){
        int jh = wv;
        const float* ar = fyrl + (l&15)*260 + (l>>4)*8;
        const float* ai = fyil + (l&15)*260 + (l>>4)*8;
        f32x4 accR = {0.f,0.f,0.f,0.f}, accI = {0.f,0.f,0.f,0.f};
        for (int kt=0; kt<8; ++kt){
            float4 r0 = *reinterpret_cast<const float4*>(ar + kt*32);
            float4 r1 = *reinterpret_cast<const float4*>(ar + kt*32 + 4);
            float4 i0 = *reinterpret_cast<const float4*>(ai + kt*32);
            float4 i1 = *reinterpret_cast<const float4*>(ai + kt*32 + 4);
            float rv[8] = {r0.x,r0.y,r0.z,r0.w,r1.x,r1.y,r1.z,r1.w};
            float iv[8] = {i0.x,i0.y,i0.z,i0.w,i1.x,i1.y,i1.z,i1.w};
            bf16x8 Rh, Rl, Ih, Il;
            #pragma unroll
            for (int e=0;e<8;e++){
                unsigned short hb = bf16_rne(rv[e]);
                Rh[e] = (short)hb;
                Rl[e] = (short)bf16_rne(rv[e] - bf16_tof(hb));
                unsigned short hb2 = bf16_rne(iv[e]);
                Ih[e] = (short)hb2;
                Il[e] = (short)bf16_rne(iv[e] - bf16_tof(hb2));
            }
            int fb = (jh*512 + kt*64 + l)*4;   // tab stride = 1024 frags * 4
            uint4 ch = *reinterpret_cast<const uint4*>(&xbh[fb]);
            uint4 cl = *reinterpret_cast<const uint4*>(&xbl[fb]);
            uint4 sh = *reinterpret_cast<const uint4*>(&xbh[fb + 4096]);
            uint4 sl = *reinterpret_cast<const uint4*>(&xbl[fb + 4096]);
            uint4 ph = *reinterpret_cast<const uint4*>(&xbh[fb + 8192]);
            uint4 pl = *reinterpret_cast<const uint4*>(&xbl[fb + 8192]);
            bf16x8 CH = __builtin_bit_cast(bf16x8, ch);
            bf16x8 CL = __builtin_bit_cast(bf16x8, cl);
            bf16x8 SH = __builtin_bit_cast(bf16x8, sh);
            bf16x8 SL = __builtin_bit_cast(bf16x8, sl);
            bf16x8 PH = __builtin_bit_cast(bf16x8, ph);
            bf16x8 PL = __builtin_bit_cast(bf16x8, pl);
            accR = __builtin_amdgcn_mfma_f32_16x16x32_bf16(Rh, CH, accR, 0,0,0);
            accR = __builtin_amdgcn_mfma_f32_16x16x32_bf16(Rh, CL, accR, 0,0,0);
            accR = __builtin_amdgcn_mfma_f32_16x16x32_bf16(Rl, CH, accR, 0,0,0);
            accR = __builtin_amdgcn_mfma_f32_16x16x32_bf16(Ih, PH, accR, 0,0,0);
            accR = __builtin_amdgcn_mfma_f32_16x16x32_bf16(Ih, PL, accR, 0,0,0);
            accR = __builtin_amdgcn_mfma_f32_16x16x32_bf16(Il, PH, accR, 0,0,0);
            accI = __builtin_amdgcn_mfma_f32_16x16x32_bf16(Rh, SH, accI, 0,0,0);
            accI = __builtin_amdgcn_mfma_f32_16x16x32_bf16(Rh, SL, accI, 0,0,0);
            accI = __builtin_amdgcn_mfma_f32_16x16x32_bf16(Rl, SH, accI, 0,0,0);
            accI = __builtin_amdgcn_mfma_f32_16x16x32_bf16(Ih, CH, accI, 0,0,0);
            accI = __builtin_amdgcn_mfma_f32_16x16x32_bf16(Ih, CL, accI, 0,0,0);
            accI = __builtin_amdgcn_mfma_f32_16x16x32_bf16(Il, CH, accI, 0,0,0);
        }
        int ob = bwv*512 + jh*16 + (l&15);
        int ky0 = (l>>4)*4;
        #pragma unroll
        for (int r=0;r<4;r++){
            fxr[ob + (ky0+r)*32] = accR[r];
            fxi[ob + (ky0+r)*32] = accI[r];
        }
    }
}

// ---- complex mode mixing (w1/w2) with mlp1 fused via LDS ----
// grid: 256 blocks = (b4, v2, ky16, jh2); 512 threads = (o32, j16)
__global__ void k_modemix(const float* __restrict__ fxr, const float* __restrict__ fxi,
                          const float* __restrict__ w1r_, const float* __restrict__ w1i_,
                          const float* __restrict__ w2r_, const float* __restrict__ w2i_,
                          const float* __restrict__ m1, float* __restrict__ g2r, float* __restrict__ g2i){
    __shared__ float glr[32*17], gli[32*17];
    int blk = blockIdx.x;
    int jh = blk&1, ky = (blk>>1)&15, v = (blk>>5)&1, b = blk>>6;
    int o = threadIdx.x>>4, jl = threadIdx.x&15;
    int j = jh*16 + jl;
    int kxi = (j<16) ? j : (j-16);
    const float* wr_ = (j<16) ? w1r_ : w2r_;
    const float* wi_ = (j<16) ? w1i_ : w2i_;
    int wbase = (o*kV + v)*256 + kxi*16 + ky;         // + i*16384
    int fbase = (b*kW*kV + v)*512 + ky*32 + j;        // + i*1024
    float re=0.f, im=0.f;
    #pragma unroll 8
    for (int i=0;i<32;i++){
        float fr=fxr[fbase+i*1024], fi=fxi[fbase+i*1024];
        float wr=wr_[wbase+i*16384], wi=wi_[wbase+i*16384];
        re += fr*wr - fi*wi;
        im += fr*wi + fi*wr;
    }
    glr[o*17+jl]=re; gli[o*17+jl]=im;
    __syncthreads();
    // mlp1: g2[o] = sum_i m1[o][i] * g[i]   (same-j mixing only)
    float r2=0.f, i2=0.f;
    #pragma unroll 8
    for (int i=0;i<32;i++){
        float m = m1[o*32+i];
        r2 += m*glr[i*17+jl];
        i2 += m*gli[i*17+jl];
    }
    int gid = ((b*kW + o)*kV + v)*512 + ky*32 + j;
    g2r[gid]=r2; g2i[gid]=i2;
}

// ---- FUSED inverse + pointwise: x-iDFT + y-irfft + mlp1b + gelu (t in LDS)
//      then mlp2(t) + ww*h + grid-term + gelu + residual.
// grid: 2048 blocks = (b4, v2, xr256); 256 threads. Kills the 128MB t round-trip.
__global__ void k_invpoint(const float* __restrict__ g2r, const float* __restrict__ g2i,
                           const float* __restrict__ xic, const float* __restrict__ xis,
                           const float* __restrict__ iyc, const float* __restrict__ iys,
                           const float* __restrict__ b1,
                           const float* h, const float* res, float* out,
                           const float* __restrict__ m2, const float* __restrict__ b2,
                           const float* __restrict__ ww_, const float* __restrict__ wb_,
                           const float* __restrict__ bw_, const float* __restrict__ bb_){
    __shared__ float frl[16*36], fil[16*36];   // [k][o] pad 36: b128 reads conflict-free
    __shared__ float tl[32*260];               // [c][y] pad 260: ph2b reads 2-lane/bank
    int tid = threadIdx.x;
    int blk = blockIdx.x;
    int b = blk>>9, v = (blk>>8)&1, xr = blk&255;

    // ---- phase 1: x-iDFT at fixed x=xr: F[o][k] = sum_j g2[o][k][j]*e^{+i th} ----
    #pragma unroll
    for (int pp=0; pp<2; pp++){
        int p = tid + pp*256;
        int o = p>>4, k = p&15;
        const float* gr_ = g2r + (((b*kW + o)*kV + v)<<9) + k*32;
        const float* gi_ = g2i + (((b*kW + o)*kV + v)<<9) + k*32;
        float re=0.f, im=0.f;
        #pragma unroll 8
        for (int j=0;j<32;j++){
            float grv=gr_[j], giv=gi_[j];
            float c=xic[j*256+xr], s=xis[j*256+xr];   // wave-uniform table reads
            re += grv*c - giv*s;
            im += grv*s + giv*c;
        }
        frl[k*36+o]=re; fil[k*36+o]=im;
    }
    __syncthreads();

    // ---- phase 2a: y-irfft, 4o x 8y tile per thread; t = gelu(acc + b1) ----
    {
        int og = tid&7, yg = tid>>3;
        int o0 = og*4, y0 = yg*8;
        float acc[4][8];
        #pragma unroll
        for (int oo=0;oo<4;oo++){
            float bb1 = b1[o0+oo];
            #pragma unroll
            for (int yy=0;yy<8;yy++) acc[oo][yy]=bb1;
        }
        #pragma unroll 4
        for (int k=0;k<16;k++){
            float4 yc0 = *reinterpret_cast<const float4*>(&iyc[k*256+y0]);
            float4 yc1 = *reinterpret_cast<const float4*>(&iyc[k*256+y0+4]);
            float4 ys0 = *reinterpret_cast<const float4*>(&iys[k*256+y0]);
            float4 ys1 = *reinterpret_cast<const float4*>(&iys[k*256+y0+4]);
            float4 fr4 = *reinterpret_cast<const float4*>(&frl[k*36+o0]);
            float4 fi4 = *reinterpret_cast<const float4*>(&fil[k*36+o0]);
            float frv[4]={fr4.x,fr4.y,fr4.z,fr4.w};
            float fiv[4]={fi4.x,fi4.y,fi4.z,fi4.w};
            #pragma unroll
            for (int oo=0;oo<4;oo++){
                acc[oo][0] += frv[oo]*yc0.x + fiv[oo]*ys0.x;
                acc[oo][1] += frv[oo]*yc0.y + fiv[oo]*ys0.y;
                acc[oo][2] += frv[oo]*yc0.z + fiv[oo]*ys0.z;
                acc[oo][3] += frv[oo]*yc0.w + fiv[oo]*ys0.w;
                acc[oo][4] += frv[oo]*yc1.x + fiv[oo]*ys1.x;
                acc[oo][5] += frv[oo]*yc1.y + fiv[oo]*ys1.y;
                acc[oo][6] += frv[oo]*yc1.z + fiv[oo]*ys1.z;
                acc[oo][7] += frv[oo]*yc1.w + fiv[oo]*ys1.w;
            }
        }
        #pragma unroll
        for (int oo=0;oo<4;oo++){
            float4 w0, w1;
            w0.x = gelu_f(acc[oo][0]); w0.y = gelu_f(acc[oo][1]);
            w0.z = gelu_f(acc[oo][2]); w0.w = gelu_f(acc[oo][3]);
            w1.x = gelu_f(acc[oo][4]); w1.y = gelu_f(acc[oo][5]);
            w1.z = gelu_f(acc[oo][6]); w1.w = gelu_f(acc[oo][7]);
            *reinterpret_cast<float4*>(&tl[(o0+oo)*260 + y0])   = w0;
            *reinterpret_cast<float4*>(&tl[(o0+oo)*260 + y0+4]) = w1;
        }
    }
    __syncthreads();

    // ---- phase 2b: pointmix (identical math to old k_pointmix) ----
    int y = tid;
    int pbase = b*(kW*CHS) + v*NPLANE + xr*256 + y;
    float gx = 9.5f + xr*(1.0f/255.0f);
    float gy = -0.5f + y*(1.0f/255.0f);
    float tv[32], hv[32];
    #pragma unroll
    for (int c=0;c<32;c++) tv[c]=tl[c*260+y];
    #pragma unroll
    for (int c=0;c<32;c++) hv[c]=h[pbase + c*CHS];
    #pragma unroll 4
    for (int o=0;o<32;o++){
        float s = b2[o]+wb_[o]+bb_[o] + bw_[o*2]*gx + bw_[o*2+1]*gy;
        #pragma unroll
        for (int c=0;c<32;c++) s += tv[c]*m2[o*32+c];
        #pragma unroll
        for (int c=0;c<32;c++) s += hv[c]*ww_[o*32+c];
        float r = gelu_f(s);
        if (res) r += res[pbase+o*CHS];
        out[pbase+o*CHS] = r;
    }
}

// ---- head via MFMA: LDS-staged h tile, fc1 split-bf16 + gelu + fc2 ----
// grid: 2048 blocks x 256 thr (R15 form — best of 8 k_head variants).
// RULE (3x: R7/R8/R14): MFMA bodies w/ fresh acc + loop-invariant A-frags must
// be FULLY unrolled w/ constant bounds. R16 wave-split: occupancy 2x but flat
// perf -> k_head is chain-bound, not occupancy-bound. Keep this version.
__global__ __launch_bounds__(256) void k_head(const float* __restrict__ h,
        const unsigned int* __restrict__ whi, const unsigned int* __restrict__ wlo,
        const float* __restrict__ fc1b, const float* __restrict__ fc2w,
        const float* __restrict__ fc2b, float* __restrict__ out){
    __shared__ float hl[32*257];   // pad 257: all 64 lanes distinct banks (2-way = free)
    int tid = threadIdx.x;
    int plane = blockIdx.x>>8, xr = blockIdx.x&255;
    int b = plane>>1, v = plane&1;
    const float* hp = h + b*(kW*CHS) + v*NPLANE + xr*256;
    #pragma unroll 8
    for (int c=0;c<32;c++) hl[c*257 + tid] = hp[c*CHS + tid];  // coalesced 1KB/instr
    __syncthreads();

    int wv = tid>>6, l = tid&63;
    int lm = l&15, lg = l>>4;
    float f2b[5];
    #pragma unroll
    for (int j=0;j<5;j++) f2b[j] = fc2b[j];

    for (int mt=0; mt<4; ++mt){
        int pxl = wv*64 + mt*16 + lm;    // local pixel for A row
        bf16x8 ah, al;
        #pragma unroll
        for (int e=0;e<8;e++){
            float a = hl[(lg*8+e)*257 + pxl];
            unsigned short hb = bf16_rne(a);
            ah[e] = (short)hb;
            al[e] = (short)bf16_rne(a - bf16_tof(hb));
        }
        float fj[4][5];
        #pragma unroll
        for (int r=0;r<4;r++)
            #pragma unroll
            for (int j=0;j<5;j++) fj[r][j]=0.f;
        for (int q=0; q<4; ++q){
            #pragma unroll
            for (int ntq=0; ntq<4; ntq++){
                int nt = q*4 + ntq;
                uint4 rh = *reinterpret_cast<const uint4*>(&whi[(nt*64+l)*4]);
                uint4 rl = *reinterpret_cast<const uint4*>(&wlo[(nt*64+l)*4]);
                bf16x8 BH = __builtin_bit_cast(bf16x8, rh);
                bf16x8 BL = __builtin_bit_cast(bf16x8, rl);
                f32x4 d = {0.f,0.f,0.f,0.f};
                d = __builtin_amdgcn_mfma_f32_16x16x32_bf16(ah, BH, d, 0,0,0);
                d = __builtin_amdgcn_mfma_f32_16x16x32_bf16(ah, BL, d, 0,0,0);
                d = __builtin_amdgcn_mfma_f32_16x16x32_bf16(al, BH, d, 0,0,0);
                int o = nt*16 + lm;
                float b1  = fc1b[o];
                float w20 = fc2w[o*5+0], w21 = fc2w[o*5+1], w22 = fc2w[o*5+2];
                float w23 = fc2w[o*5+3], w24 = fc2w[o*5+4];
                #pragma unroll
                for (int r=0;r<4;r++){
                    float u = gelu_f(d[r] + b1);
                    fj[r][0] += u*w20; fj[r][1] += u*w21; fj[r][2] += u*w22;
                    fj[r][3] += u*w23; fj[r][4] += u*w24;
                }
            }
        }
        // reduce over the 16 o-lanes (lm bits)
        #pragma unroll
        for (int m=1; m<16; m<<=1){
            #pragma unroll
            for (int r=0;r<4;r++){
                #pragma unroll
                for (int j=0;j<5;j++) fj[r][j] += __shfl_xor(fj[r][j], m, 64);
            }
        }
        if (lm == 0){
            int prow = blockIdx.x*256 + wv*64 + mt*16 + lg*4;  // D rows m = lg*4+r
            #pragma unroll
            for (int r=0;r<4;r++){
                long ob = (long)(prow+r)*5;
                #pragma unroll
                for (int j=0;j<5;j++) out[ob+j] = fj[r][j] + f2b[j];
            }
        }
    }
}

extern "C" void kernel_launch(void* const* d_in, const int* in_sizes, int n_in,
                              void* d_out, int out_size, void* d_ws, size_t ws_size,
                              hipStream_t stream){
    const float* x    =(const float*)d_in[0];
    const float* fc0w =(const float*)d_in[1];
    const float* fc0b =(const float*)d_in[2];
    const float* w1r  =(const float*)d_in[3];
    const float* w1i  =(const float*)d_in[4];
    const float* w2r  =(const float*)d_in[5];
    const float* w2i  =(const float*)d_in[6];
    const float* m1w  =(const float*)d_in[7];
    const float* m1b  =(const float*)d_in[8];
    const float* m2w  =(const float*)d_in[9];
    const float* m2b  =(const float*)d_in[10];
    const float* ww   =(const float*)d_in[11];
    const float* wb   =(const float*)d_in[12];
    const float* bw   =(const float*)d_in[13];
    const float* bb   =(const float*)d_in[14];
    const float* fc1w =(const float*)d_in[15];
    const float* fc1b =(const float*)d_in[16];
    const float* fc2w =(const float*)d_in[17];
    const float* fc2b =(const float*)d_in[18];

    float* ws = (float*)d_ws;
    float* big[3] = {ws+OFF_BIG0, ws+OFF_BIG1, ws+OFF_BIG2};
    float* fxr = ws+OFF_FXR; float* fxi = ws+OFF_FXI;
    float* gr  = ws+OFF_GR;  float* gi  = ws+OFF_GI;

    k_tables<<<32,256,0,stream>>>(ws, fc1w);
    k_fc0<<<2048,256,0,stream>>>(x, fc0w, fc0b, big[0]);

    // schedule: {in, out, res}
    const int s_in [6] = {0,0,2,2,2,0};
    const int s_out[6] = {0,2,2,2,0,0};
    const int s_res[6] = {-1,-1,0,-1,-1,2};

    for (int blk=0; blk<6; ++blk){
        float* in   = big[s_in[blk]];
        float* outb = big[s_out[blk]];
        const float* resp = (s_res[blk] < 0) ? nullptr : big[s_res[blk]];
        k_fwdfft<<<256,512,0,stream>>>(in,
            (const unsigned int*)(ws+OFF_YAH), (const unsigned int*)(ws+OFF_YAL),
            (const unsigned int*)(ws+OFF_XBH), (const unsigned int*)(ws+OFF_XBL),
            fxr, fxi);
        k_modemix<<<256,512,0,stream>>>(fxr, fxi,
            w1r+blk*524288, w1i+blk*524288, w2r+blk*524288, w2i+blk*524288,
            m1w+blk*1024, gr, gi);
        k_invpoint<<<2048,256,0,stream>>>(gr, gi, ws+OFF_TIC, ws+OFF_TIS,
            ws+OFF_IYC, ws+OFF_IYS, m1b+blk*32,
            in, resp, outb,
            m2w+blk*1024, m2b+blk*32, ww+blk*1024, wb+blk*32, bw+blk*64, bb+blk*32);
    }
    k_head<<<2048,256,0,stream>>>(big[0],
        (const unsigned int*)(ws+OFF_WHI), (const unsigned int*)(ws+OFF_WLO),
        fc1b, fc2w, fc2b, (float*)d_out);
}

// Round 18
// 1225.953 us; speedup vs baseline: 1.0169x; 1.0062x over previous
//
#include <hip/hip_runtime.h>

// ---- problem constants ----
#define kB 4
#define kV 2
#define kS 256
#define kW 32
#define kM 16
#define kNB 6
#define kTIN 10
#define kSTEP 5

#define NPLANE 65536            // S*S
#define NBWV   (kB*kW*kV)       // 256
#define BIGN   (kB*kW*kV*NPLANE)// 16777216 floats per state buffer
#define CHS    (kV*NPLANE)      // channel stride = 131072

// ---- workspace layout (float offsets) ----
#define OFF_BIG0 0
#define OFF_BIG1 16777216
#define OFF_BIG2 33554432
#define OFF_FXR  52428800   // [bwv][ky16][j32] = 131072
#define OFF_FXI  52559872
#define OFF_GR   52690944
#define OFF_GI   52822016
#define OFF_TIC  52969472   // x inverse [j][x] 8192
#define OFF_TIS  52977664
#define OFF_IYC  52985856   // y inverse [k][y] 4096
#define OFF_IYS  52989952
#define OFF_WHI  52994048   // fc1 hi-bf16 frags [nt16][lane64][4 uints] = 4096
#define OFF_WLO  52998144   // fc1 lo-bf16 frags = 4096
#define OFF_YAH  53002240   // ydft table A-frags hi [mt2][kt8][lane64][4u] = 4096
#define OFF_YAL  53006336   // ydft table A-frags lo = 4096
#define OFF_XBH  53010432   // xdft table B-frags hi [tab3][jh2][kt8][l64][4u] = 12288
#define OFF_XBL  53022720   // xdft table B-frags lo = 12288
// total 53035008 floats ~= 202.3 MiB

typedef short bf16x8 __attribute__((ext_vector_type(8)));
typedef float f32x4 __attribute__((ext_vector_type(4)));

__device__ __forceinline__ unsigned short bf16_rne(float f){
    union { float f; unsigned int u; } x; x.f = f;
    unsigned int u = x.u + 0x7fffu + ((x.u>>16)&1u);
    return (unsigned short)(u>>16);
}
__device__ __forceinline__ float bf16_tof(unsigned short h){
    union { unsigned int u; float f; } x; x.u = ((unsigned int)h)<<16;
    return x.f;
}

// Fast exact-erf gelu: A&S 7.1.26, |erf err| <= 1.5e-7. Native rcp+exp.
__device__ __forceinline__ float gelu_f(float x){
    float z = fabsf(x) * 0.70710678118654752f;
    float t = __builtin_amdgcn_rcpf(1.0f + 0.3275911f*z);
    float poly = t*(0.254829592f + t*(-0.284496736f + t*(1.421413741f + t*(-1.453152027f + t*1.061405429f))));
    float e = __expf(-z*z);
    float erf_abs = 1.0f - poly*e;
    float ph = (x >= 0.0f) ? (1.0f + erf_abs) : (1.0f - erf_abs);
    return 0.5f * x * ph;
}

// ---- DFT tables + fc1 / ydft / xdft bf16 fragment packing ----
__global__ void k_tables(float* ws, const float* __restrict__ fc1w){
    const double PI = 3.14159265358979323846;
    int t = blockIdx.x*256 + threadIdx.x; // 8192 threads
    if (t < 8192){
        // inverse x-DFT, [j][x]: e^{+i 2pi kx x /256}
        int j2 = t>>8, x2 = t&255;
        int kx2 = (j2<16) ? j2 : (224+j2);
        int p2 = (kx2*x2)&255;
        double a2 = (double)p2*(PI/128.0);
        ws[OFF_TIC+t] = (float)cos(a2);
        ws[OFF_TIS+t] = (float)sin(a2);
    }
    if (t < 4096){
        // y-irfft basis [k][y], scale 1/65536 folds both ifft normalizations
        int k = t>>8, y = t&255;
        int p = (k*y)&255;
        double a = (double)p*(PI/128.0);
        float sc = 1.0f/65536.0f;
        ws[OFF_IYC+t] = (k==0 ? 1.0f : 2.0f*(float)cos(a))*sc;
        ws[OFF_IYS+t] = (k==0 ? 0.0f : -2.0f*(float)sin(a))*sc;
    }
    if (t < 1024){
        // fc1 weight fragments for MFMA: tile nt, lane l:
        //   o = nt*16 + (l&15), channels c = (l>>4)*8 .. +7
        int nt = t>>6, l = t&63;
        int o = nt*16 + (l&15), c0 = (l>>4)*8;
        unsigned int hw[4], lw[4];
        #pragma unroll
        for (int e2=0; e2<4; e2++){
            float f0 = fc1w[(c0+2*e2  )*256 + o];
            float f1 = fc1w[(c0+2*e2+1)*256 + o];
            unsigned short h0 = bf16_rne(f0), h1 = bf16_rne(f1);
            unsigned short l0 = bf16_rne(f0 - bf16_tof(h0));
            unsigned short l1 = bf16_rne(f1 - bf16_tof(h1));
            hw[e2] = (unsigned int)h0 | ((unsigned int)h1<<16);
            lw[e2] = (unsigned int)l0 | ((unsigned int)l1<<16);
        }
        unsigned int* whi = (unsigned int*)(ws+OFF_WHI);
        unsigned int* wlo = (unsigned int*)(ws+OFF_WLO);
        #pragma unroll
        for (int e2=0; e2<4; e2++){
            whi[t*4+e2] = hw[e2];
            wlo[t*4+e2] = lw[e2];
        }
    }
    if (t < 1024){
        // ydft A-fragments: t = mt*512 + kt*64 + l
        //   mt=0: cos(2pi ky y/256); mt=1: -sin(...)
        //   lane l: m-row ky = l&15, k = kt*32 + (l>>4)*8 + e
        int mt = t>>9, kt = (t>>6)&7, l = t&63;
        int ky = l&15;
        unsigned int* yah = (unsigned int*)(ws+OFF_YAH);
        unsigned int* yal = (unsigned int*)(ws+OFF_YAL);
        #pragma unroll
        for (int e2=0; e2<4; e2++){
            int y0 = kt*32 + (l>>4)*8 + 2*e2;
            double a0 = (double)((ky*y0)&255)*(PI/128.0);
            double a1 = (double)((ky*(y0+1))&255)*(PI/128.0);
            float v0 = (mt==0) ? (float)cos(a0) : -(float)sin(a0);
            float v1 = (mt==0) ? (float)cos(a1) : -(float)sin(a1);
            unsigned short h0 = bf16_rne(v0), h1 = bf16_rne(v1);
            unsigned short s0 = bf16_rne(v0 - bf16_tof(h0));
            unsigned short s1 = bf16_rne(v1 - bf16_tof(h1));
            yah[t*4+e2] = (unsigned int)h0 | ((unsigned int)h1<<16);
            yal[t*4+e2] = (unsigned int)s0 | ((unsigned int)s1<<16);
        }
    }
    if (t < 3072){
        // xdft B-fragments: t = tab*1024 + jh*512 + kt*64 + l
        //   tab0: cos(2pi kx x/256); tab1: -sin; tab2: +sin
        //   lane l: n-col j = jh*16 + (l&15), k = x = kt*32 + (l>>4)*8 + e
        int tab = t>>10, jh = (t>>9)&1, kt = (t>>6)&7, l = t&63;
        int j = jh*16 + (l&15);
        int kx = (j<16) ? j : (224+j);
        unsigned int* xbh = (unsigned int*)(ws+OFF_XBH);
        unsigned int* xbl = (unsigned int*)(ws+OFF_XBL);
        #pragma unroll
        for (int e2=0; e2<4; e2++){
            int x0 = kt*32 + (l>>4)*8 + 2*e2;
            double a0 = (double)((kx*x0)&255)*(PI/128.0);
            double a1 = (double)((kx*(x0+1))&255)*(PI/128.0);
            float v0, v1;
            if (tab==0){ v0=(float)cos(a0); v1=(float)cos(a1); }
            else if (tab==1){ v0=-(float)sin(a0); v1=-(float)sin(a1); }
            else { v0=(float)sin(a0); v1=(float)sin(a1); }
            unsigned short h0 = bf16_rne(v0), h1 = bf16_rne(v1);
            unsigned short s0 = bf16_rne(v0 - bf16_tof(h0));
            unsigned short s1 = bf16_rne(v1 - bf16_tof(h1));
            xbh[t*4+e2] = (unsigned int)h0 | ((unsigned int)h1<<16);
            xbl[t*4+e2] = (unsigned int)s0 | ((unsigned int)s1<<16);
        }
    }
}

// ---- fc0 + grid concat + transpose to (B,W,V,S,S) ----
__global__ void k_fc0(const float* __restrict__ x, const float* __restrict__ w,
                      const float* __restrict__ bias, float* __restrict__ h0){
    int plane = blockIdx.x>>8, xr = blockIdx.x&255, y = threadIdx.x;
    int xy = xr*256+y;
    long p = (long)plane*NPLANE + xy;
    float f[12];
    #pragma unroll
    for (int i=0;i<10;i++) f[i]=x[p*10+i];
    f[10] = 9.5f + xr*(1.0f/255.0f);
    f[11] = -0.5f + y*(1.0f/255.0f);
    float acc[32];
    #pragma unroll
    for (int o=0;o<32;o++) acc[o]=bias[o];
    #pragma unroll
    for (int c=0;c<12;c++){
        float fv=f[c];
        #pragma unroll
        for (int o=0;o<32;o++) acc[o]+=fv*w[c*32+o];
    }
    int b=plane>>1, v=plane&1;
    int base = b*(kW*CHS) + v*NPLANE + xy;
    #pragma unroll
    for (int o=0;o<32;o++) h0[base + o*CHS]=acc[o];
}

// ---- FUSED forward FFT: ydft (MFMA) -> LDS -> xdft (MFMA) ----
// grid: 256 blocks = bwv; 512 threads = 8 waves.
__global__ __launch_bounds__(512) void k_fwdfft(const float* __restrict__ h,
        const unsigned int* __restrict__ yah, const unsigned int* __restrict__ yal,
        const unsigned int* __restrict__ xbh, const unsigned int* __restrict__ xbl,
        float* __restrict__ fxr, float* __restrict__ fxi){
    __shared__ float fyrl[16*260], fyil[16*260];
    int bwv = blockIdx.x;
    int tid = threadIdx.x;
    int wv = tid>>6, l = tid&63;

    for (int half=0; half<2; ++half){
        int nt = wv*2 + half;            // 0..15
        int x = nt*16 + (l&15);
        int klo = (l>>4)*8;
        const float* hp = h + bwv*NPLANE + x*256 + klo;
        f32x4 accR = {0.f,0.f,0.f,0.f}, accI = {0.f,0.f,0.f,0.f};
        for (int kt=0; kt<8; ++kt){
            float4 b0 = *reinterpret_cast<const float4*>(hp + kt*32);
            float4 b1 = *reinterpret_cast<const float4*>(hp + kt*32 + 4);
            float bv[8] = {b0.x,b0.y,b0.z,b0.w,b1.x,b1.y,b1.z,b1.w};
            bf16x8 bh, bl;
            #pragma unroll
            for (int e=0;e<8;e++){
                unsigned short hb = bf16_rne(bv[e]);
                bh[e] = (short)hb;
                bl[e] = (short)bf16_rne(bv[e] - bf16_tof(hb));
            }
            uint4 a0h = *reinterpret_cast<const uint4*>(&yah[(kt*64+l)*4]);
            uint4 a0l = *reinterpret_cast<const uint4*>(&yal[(kt*64+l)*4]);
            uint4 a1h = *reinterpret_cast<const uint4*>(&yah[(512 + kt*64 + l)*4]);
            uint4 a1l = *reinterpret_cast<const uint4*>(&yal[(512 + kt*64 + l)*4]);
            bf16x8 AH0 = __builtin_bit_cast(bf16x8, a0h);
            bf16x8 AL0 = __builtin_bit_cast(bf16x8, a0l);
            bf16x8 AH1 = __builtin_bit_cast(bf16x8, a1h);
            bf16x8 AL1 = __builtin_bit_cast(bf16x8, a1l);
            accR = __builtin_amdgcn_mfma_f32_16x16x32_bf16(AH0, bh, accR, 0,0,0);
            accR = __builtin_amdgcn_mfma_f32_16x16x32_bf16(AH0, bl, accR, 0,0,0);
            accR = __builtin_amdgcn_mfma_f32_16x16x32_bf16(AL0, bh, accR, 0,0,0);
            accI = __builtin_amdgcn_mfma_f32_16x16x32_bf16(AH1, bh, accI, 0,0,0);
            accI = __builtin_amdgcn_mfma_f32_16x16x32_bf16(AH1, bl, accI, 0,0,0);
            accI = __builtin_amdgcn_mfma_f32_16x16x32_bf16(AL1, bh, accI, 0,0,0);
        }
        int ky0 = (l>>4)*4;
        #pragma unroll
        for (int r=0;r<4;r++){
            fyrl[(ky0+r)*260 + x] = accR[r];
            fyil[(ky0+r)*260 + x] = accI[r];
        }
    }
    __syncthreads();

    if (wv < 2){
        int jh = wv;
        const float* ar = fyrl + (l&15)*260 + (l>>4)*8;
        const float* ai = fyil + (l&15)*260 + (l>>4)*8;
        f32x4 accR = {0.f,0.f,0.f,0.f}, accI = {0.f,0.f,0.f,0.f};
        for (int kt=0; kt<8; ++kt){
            float4 r0 = *reinterpret_cast<const float4*>(ar + kt*32);
            float4 r1 = *reinterpret_cast<const float4*>(ar + kt*32 + 4);
            float4 i0 = *reinterpret_cast<const float4*>(ai + kt*32);
            float4 i1 = *reinterpret_cast<const float4*>(ai + kt*32 + 4);
            float rv[8] = {r0.x,r0.y,r0.z,r0.w,r1.x,r1.y,r1.z,r1.w};
            float iv[8] = {i0.x,i0.y,i0.z,i0.w,i1.x,i1.y,i1.z,i1.w};
            bf16x8 Rh, Rl, Ih, Il;
            #pragma unroll
            for (int e=0;e<8;e++){
                unsigned short hb = bf16_rne(rv[e]);
                Rh[e] = (short)hb;
                Rl[e] = (short)bf16_rne(rv[e] - bf16_tof(hb));
                unsigned short hb2 = bf16_rne(iv[e]);
                Ih[e] = (short)hb2;
                Il[e] = (short)bf16_rne(iv[e] - bf16_tof(hb2));
            }
            int fb = (jh*512 + kt*64 + l)*4;   // tab stride = 1024 frags * 4
            uint4 ch = *reinterpret_cast<const uint4*>(&xbh[fb]);
            uint4 cl = *reinterpret_cast<const uint4*>(&xbl[fb]);
            uint4 sh = *reinterpret_cast<const uint4*>(&xbh[fb + 4096]);
            uint4 sl = *reinterpret_cast<const uint4*>(&xbl[fb + 4096]);
            uint4 ph = *reinterpret_cast<const uint4*>(&xbh[fb + 8192]);
            uint4 pl = *reinterpret_cast<const uint4*>(&xbl[fb + 8192]);
            bf16x8 CH = __builtin_bit_cast(bf16x8, ch);
            bf16x8 CL = __builtin_bit_cast(bf16x8, cl);
            bf16x8 SH = __builtin_bit_cast(bf16x8, sh);
            bf16x8 SL = __builtin_bit_cast(bf16x8, sl);
            bf16x8 PH = __builtin_bit_cast(bf16x8, ph);
            bf16x8 PL = __builtin_bit_cast(bf16x8, pl);
            accR = __builtin_amdgcn_mfma_f32_16x16x32_bf16(Rh, CH, accR, 0,0,0);
            accR = __builtin_amdgcn_mfma_f32_16x16x32_bf16(Rh, CL, accR, 0,0,0);
            accR = __builtin_amdgcn_mfma_f32_16x16x32_bf16(Rl, CH, accR, 0,0,0);
            accR = __builtin_amdgcn_mfma_f32_16x16x32_bf16(Ih, PH, accR, 0,0,0);
            accR = __builtin_amdgcn_mfma_f32_16x16x32_bf16(Ih, PL, accR, 0,0,0);
            accR = __builtin_amdgcn_mfma_f32_16x16x32_bf16(Il, PH, accR, 0,0,0);
            accI = __builtin_amdgcn_mfma_f32_16x16x32_bf16(Rh, SH, accI, 0,0,0);
            accI = __builtin_amdgcn_mfma_f32_16x16x32_bf16(Rh, SL, accI, 0,0,0);
            accI = __builtin_amdgcn_mfma_f32_16x16x32_bf16(Rl, SH, accI, 0,0,0);
            accI = __builtin_amdgcn_mfma_f32_16x16x32_bf16(Ih, CH, accI, 0,0,0);
            accI = __builtin_amdgcn_mfma_f32_16x16x32_bf16(Ih, CL, accI, 0,0,0);
            accI = __builtin_amdgcn_mfma_f32_16x16x32_bf16(Il, CH, accI, 0,0,0);
        }
        int ob = bwv*512 + jh*16 + (l&15);
        int ky0 = (l>>4)*4;
        #pragma unroll
        for (int r=0;r<4;r++){
            fxr[ob + (ky0+r)*32] = accR[r];
            fxi[ob + (ky0+r)*32] = accI[r];
        }
    }
}

// ---- complex mode mixing (w1/w2) with mlp1 fused via LDS ----
// grid: 256 blocks = (b4, v2, ky16, jh2); 512 threads = (o32, j16)
__global__ void k_modemix(const float* __restrict__ fxr, const float* __restrict__ fxi,
                          const float* __restrict__ w1r_, const float* __restrict__ w1i_,
                          const float* __restrict__ w2r_, const float* __restrict__ w2i_,
                          const float* __restrict__ m1, float* __restrict__ g2r, float* __restrict__ g2i){
    __shared__ float glr[32*17], gli[32*17];
    int blk = blockIdx.x;
    int jh = blk&1, ky = (blk>>1)&15, v = (blk>>5)&1, b = blk>>6;
    int o = threadIdx.x>>4, jl = threadIdx.x&15;
    int j = jh*16 + jl;
    int kxi = (j<16) ? j : (j-16);
    const float* wr_ = (j<16) ? w1r_ : w2r_;
    const float* wi_ = (j<16) ? w1i_ : w2i_;
    int wbase = (o*kV + v)*256 + kxi*16 + ky;         // + i*16384
    int fbase = (b*kW*kV + v)*512 + ky*32 + j;        // + i*1024
    float re=0.f, im=0.f;
    #pragma unroll 8
    for (int i=0;i<32;i++){
        float fr=fxr[fbase+i*1024], fi=fxi[fbase+i*1024];
        float wr=wr_[wbase+i*16384], wi=wi_[wbase+i*16384];
        re += fr*wr - fi*wi;
        im += fr*wi + fi*wr;
    }
    glr[o*17+jl]=re; gli[o*17+jl]=im;
    __syncthreads();
    // mlp1: g2[o] = sum_i m1[o][i] * g[i]   (same-j mixing only)
    float r2=0.f, i2=0.f;
    #pragma unroll 8
    for (int i=0;i<32;i++){
        float m = m1[o*32+i];
        r2 += m*glr[i*17+jl];
        i2 += m*gli[i*17+jl];
    }
    int gid = ((b*kW + o)*kV + v)*512 + ky*32 + j;
    g2r[gid]=r2; g2i[gid]=i2;
}

// ---- FUSED inverse + pointwise: x-iDFT + y-irfft + mlp1b + gelu (t in LDS)
//      then mlp2(t) + ww*h + grid-term + gelu + residual.
// grid: 2048 blocks = (b4, v2, xr256); 256 threads. Kills the 128MB t round-trip.
__global__ void k_invpoint(const float* __restrict__ g2r, const float* __restrict__ g2i,
                           const float* __restrict__ xic, const float* __restrict__ xis,
                           const float* __restrict__ iyc, const float* __restrict__ iys,
                           const float* __restrict__ b1,
                           const float* h, const float* res, float* out,
                           const float* __restrict__ m2, const float* __restrict__ b2,
                           const float* __restrict__ ww_, const float* __restrict__ wb_,
                           const float* __restrict__ bw_, const float* __restrict__ bb_){
    __shared__ float frl[16*36], fil[16*36];   // [k][o] pad 36: b128 reads conflict-free
    __shared__ float tl[32*260];               // [c][y] pad 260: ph2b reads 2-lane/bank
    int tid = threadIdx.x;
    int blk = blockIdx.x;
    int b = blk>>9, v = (blk>>8)&1, xr = blk&255;

    // ---- phase 1: x-iDFT at fixed x=xr: F[o][k] = sum_j g2[o][k][j]*e^{+i th} ----
    #pragma unroll
    for (int pp=0; pp<2; pp++){
        int p = tid + pp*256;
        int o = p>>4, k = p&15;
        const float* gr_ = g2r + (((b*kW + o)*kV + v)<<9) + k*32;
        const float* gi_ = g2i + (((b*kW + o)*kV + v)<<9) + k*32;
        float re=0.f, im=0.f;
        #pragma unroll 8
        for (int j=0;j<32;j++){
            float grv=gr_[j], giv=gi_[j];
            float c=xic[j*256+xr], s=xis[j*256+xr];   // wave-uniform table reads
            re += grv*c - giv*s;
            im += grv*s + giv*c;
        }
        frl[k*36+o]=re; fil[k*36+o]=im;
    }
    __syncthreads();

    // ---- phase 2a: y-irfft, 4o x 8y tile per thread; t = gelu(acc + b1) ----
    {
        int og = tid&7, yg = tid>>3;
        int o0 = og*4, y0 = yg*8;
        float acc[4][8];
        #pragma unroll
        for (int oo=0;oo<4;oo++){
            float bb1 = b1[o0+oo];
            #pragma unroll
            for (int yy=0;yy<8;yy++) acc[oo][yy]=bb1;
        }
        #pragma unroll 4
        for (int k=0;k<16;k++){
            float4 yc0 = *reinterpret_cast<const float4*>(&iyc[k*256+y0]);
            float4 yc1 = *reinterpret_cast<const float4*>(&iyc[k*256+y0+4]);
            float4 ys0 = *reinterpret_cast<const float4*>(&iys[k*256+y0]);
            float4 ys1 = *reinterpret_cast<const float4*>(&iys[k*256+y0+4]);
            float4 fr4 = *reinterpret_cast<const float4*>(&frl[k*36+o0]);
            float4 fi4 = *reinterpret_cast<const float4*>(&fil[k*36+o0]);
            float frv[4]={fr4.x,fr4.y,fr4.z,fr4.w};
            float fiv[4]={fi4.x,fi4.y,fi4.z,fi4.w};
            #pragma unroll
            for (int oo=0;oo<4;oo++){
                acc[oo][0] += frv[oo]*yc0.x + fiv[oo]*ys0.x;
                acc[oo][1] += frv[oo]*yc0.y + fiv[oo]*ys0.y;
                acc[oo][2] += frv[oo]*yc0.z + fiv[oo]*ys0.z;
                acc[oo][3] += frv[oo]*yc0.w + fiv[oo]*ys0.w;
                acc[oo][4] += frv[oo]*yc1.x + fiv[oo]*ys1.x;
                acc[oo][5] += frv[oo]*yc1.y + fiv[oo]*ys1.y;
                acc[oo][6] += frv[oo]*yc1.z + fiv[oo]*ys1.z;
                acc[oo][7] += frv[oo]*yc1.w + fiv[oo]*ys1.w;
            }
        }
        #pragma unroll
        for (int oo=0;oo<4;oo++){
            float4 w0, w1;
            w0.x = gelu_f(acc[oo][0]); w0.y = gelu_f(acc[oo][1]);
            w0.z = gelu_f(acc[oo][2]); w0.w = gelu_f(acc[oo][3]);
            w1.x = gelu_f(acc[oo][4]); w1.y = gelu_f(acc[oo][5]);
            w1.z = gelu_f(acc[oo][6]); w1.w = gelu_f(acc[oo][7]);
            *reinterpret_cast<float4*>(&tl[(o0+oo)*260 + y0])   = w0;
            *reinterpret_cast<float4*>(&tl[(o0+oo)*260 + y0+4]) = w1;
        }
    }
    __syncthreads();

    // ---- phase 2b: pointmix (identical math to old k_pointmix) ----
    int y = tid;
    int pbase = b*(kW*CHS) + v*NPLANE + xr*256 + y;
    float gx = 9.5f + xr*(1.0f/255.0f);
    float gy = -0.5f + y*(1.0f/255.0f);
    float tv[32], hv[32];
    #pragma unroll
    for (int c=0;c<32;c++) tv[c]=tl[c*260+y];
    #pragma unroll
    for (int c=0;c<32;c++) hv[c]=h[pbase + c*CHS];
    #pragma unroll 4
    for (int o=0;o<32;o++){
        float s = b2[o]+wb_[o]+bb_[o] + bw_[o*2]*gx + bw_[o*2+1]*gy;
        #pragma unroll
        for (int c=0;c<32;c++) s += tv[c]*m2[o*32+c];
        #pragma unroll
        for (int c=0;c<32;c++) s += hv[c]*ww_[o*32+c];
        float r = gelu_f(s);
        if (res) r += res[pbase+o*CHS];
        out[pbase+o*CHS] = r;
    }
}

// ---- head via MFMA: LDS-staged h tile, fc1 split-bf16 + gelu + fc2 ----
// grid: 2048 blocks x 256 thr (R15 form — best of 8 k_head variants).
// RULE (3x: R7/R8/R14): MFMA bodies w/ fresh acc + loop-invariant A-frags must
// be FULLY unrolled w/ constant bounds. R16: occupancy 2x but flat -> chain-
// bound. R18: drop the al*BH (input-lo) MFMA — final layer, error budget
// ~+3e-4 — to shorten the serial chain 3->2 MFMAs per nt.
__global__ __launch_bounds__(256) void k_head(const float* __restrict__ h,
        const unsigned int* __restrict__ whi, const unsigned int* __restrict__ wlo,
        const float* __restrict__ fc1b, const float* __restrict__ fc2w,
        const float* __restrict__ fc2b, float* __restrict__ out){
    __shared__ float hl[32*257];   // pad 257: all 64 lanes distinct banks (2-way = free)
    int tid = threadIdx.x;
    int plane = blockIdx.x>>8, xr = blockIdx.x&255;
    int b = plane>>1, v = plane&1;
    const float* hp = h + b*(kW*CHS) + v*NPLANE + xr*256;
    #pragma unroll 8
    for (int c=0;c<32;c++) hl[c*257 + tid] = hp[c*CHS + tid];  // coalesced 1KB/instr
    __syncthreads();

    int wv = tid>>6, l = tid&63;
    int lm = l&15, lg = l>>4;
    float f2b[5];
    #pragma unroll
    for (int j=0;j<5;j++) f2b[j] = fc2b[j];

    for (int mt=0; mt<4; ++mt){
        int pxl = wv*64 + mt*16 + lm;    // local pixel for A row
        bf16x8 ah;
        #pragma unroll
        for (int e=0;e<8;e++){
            float a = hl[(lg*8+e)*257 + pxl];
            ah[e] = (short)bf16_rne(a);
        }
        float fj[4][5];
        #pragma unroll
        for (int r=0;r<4;r++)
            #pragma unroll
            for (int j=0;j<5;j++) fj[r][j]=0.f;
        for (int q=0; q<4; ++q){
            #pragma unroll
            for (int ntq=0; ntq<4; ntq++){
                int nt = q*4 + ntq;
                uint4 rh = *reinterpret_cast<const uint4*>(&whi[(nt*64+l)*4]);
                uint4 rl = *reinterpret_cast<const uint4*>(&wlo[(nt*64+l)*4]);
                bf16x8 BH = __builtin_bit_cast(bf16x8, rh);
                bf16x8 BL = __builtin_bit_cast(bf16x8, rl);
                f32x4 d = {0.f,0.f,0.f,0.f};
                d = __builtin_amdgcn_mfma_f32_16x16x32_bf16(ah, BH, d, 0,0,0);
                d = __builtin_amdgcn_mfma_f32_16x16x32_bf16(ah, BL, d, 0,0,0);
                int o = nt*16 + lm;
                float b1  = fc1b[o];
                float w20 = fc2w[o*5+0], w21 = fc2w[o*5+1], w22 = fc2w[o*5+2];
                float w23 = fc2w[o*5+3], w24 = fc2w[o*5+4];
                #pragma unroll
                for (int r=0;r<4;r++){
                    float u = gelu_f(d[r] + b1);
                    fj[r][0] += u*w20; fj[r][1] += u*w21; fj[r][2] += u*w22;
                    fj[r][3] += u*w23; fj[r][4] += u*w24;
                }
            }
        }
        // reduce over the 16 o-lanes (lm bits)
        #pragma unroll
        for (int m=1; m<16; m<<=1){
            #pragma unroll
            for (int r=0;r<4;r++){
                #pragma unroll
                for (int j=0;j<5;j++) fj[r][j] += __shfl_xor(fj[r][j], m, 64);
            }
        }
        if (lm == 0){
            int prow = blockIdx.x*256 + wv*64 + mt*16 + lg*4;  // D rows m = lg*4+r
            #pragma unroll
            for (int r=0;r<4;r++){
                long ob = (long)(prow+r)*5;
                #pragma unroll
                for (int j=0;j<5;j++) out[ob+j] = fj[r][j] + f2b[j];
            }
        }
    }
}

extern "C" void kernel_launch(void* const* d_in, const int* in_sizes, int n_in,
                              void* d_out, int out_size, void* d_ws, size_t ws_size,
                              hipStream_t stream){
    const float* x    =(const float*)d_in[0];
    const float* fc0w =(const float*)d_in[1];
    const float* fc0b =(const float*)d_in[2];
    const float* w1r  =(const float*)d_in[3];
    const float* w1i  =(const float*)d_in[4];
    const float* w2r  =(const float*)d_in[5];
    const float* w2i  =(const float*)d_in[6];
    const float* m1w  =(const float*)d_in[7];
    const float* m1b  =(const float*)d_in[8];
    const float* m2w  =(const float*)d_in[9];
    const float* m2b  =(const float*)d_in[10];
    const float* ww   =(const float*)d_in[11];
    const float* wb   =(const float*)d_in[12];
    const float* bw   =(const float*)d_in[13];
    const float* bb   =(const float*)d_in[14];
    const float* fc1w =(const float*)d_in[15];
    const float* fc1b =(const float*)d_in[16];
    const float* fc2w =(const float*)d_in[17];
    const float* fc2b =(const float*)d_in[18];

    float* ws = (float*)d_ws;
    float* big[3] = {ws+OFF_BIG0, ws+OFF_BIG1, ws+OFF_BIG2};
    float* fxr = ws+OFF_FXR; float* fxi = ws+OFF_FXI;
    float* gr  = ws+OFF_GR;  float* gi  = ws+OFF_GI;

    k_tables<<<32,256,0,stream>>>(ws, fc1w);
    k_fc0<<<2048,256,0,stream>>>(x, fc0w, fc0b, big[0]);

    // schedule: {in, out, res}
    const int s_in [6] = {0,0,2,2,2,0};
    const int s_out[6] = {0,2,2,2,0,0};
    const int s_res[6] = {-1,-1,0,-1,-1,2};

    for (int blk=0; blk<6; ++blk){
        float* in   = big[s_in[blk]];
        float* outb = big[s_out[blk]];
        const float* resp = (s_res[blk] < 0) ? nullptr : big[s_res[blk]];
        k_fwdfft<<<256,512,0,stream>>>(in,
            (const unsigned int*)(ws+OFF_YAH), (const unsigned int*)(ws+OFF_YAL),
            (const unsigned int*)(ws+OFF_XBH), (const unsigned int*)(ws+OFF_XBL),
            fxr, fxi);
        k_modemix<<<256,512,0,stream>>>(fxr, fxi,
            w1r+blk*524288, w1i+blk*524288, w2r+blk*524288, w2i+blk*524288,
            m1w+blk*1024, gr, gi);
        k_invpoint<<<2048,256,0,stream>>>(gr, gi, ws+OFF_TIC, ws+OFF_TIS,
            ws+OFF_IYC, ws+OFF_IYS, m1b+blk*32,
            in, resp, outb,
            m2w+blk*1024, m2b+blk*32, ww+blk*1024, wb+blk*32, bw+blk*64, bb+blk*32);
    }
    k_head<<<2048,256,0,stream>>>(big[0],
        (const unsigned int*)(ws+OFF_WHI), (const unsigned int*)(ws+OFF_WLO),
        fc1b, fc2w, fc2b, (float*)d_out);
}

// Round 19
// 1001.135 us; speedup vs baseline: 1.2453x; 1.2246x over previous
//
#include <hip/hip_runtime.h>

// ---- problem constants ----
#define kB 4
#define kV 2
#define kS 256
#define kW 32
#define kM 16
#define kNB 6
#define kTIN 10
#define kSTEP 5

#define NPLANE 65536            // S*S
#define NBWV   (kB*kW*kV)       // 256
#define BIGN   (kB*kW*kV*NPLANE)// 16777216 floats per state buffer
#define CHS    (kV*NPLANE)      // channel stride = 131072

// ---- workspace layout (float offsets) ----
#define OFF_BIG0 0
#define OFF_BIG1 16777216
#define OFF_BIG2 33554432
#define OFF_FXR  52428800   // [bwv][ky16][j32] = 131072
#define OFF_FXI  52559872
#define OFF_GR   52690944
#define OFF_GI   52822016
#define OFF_TIC  52969472   // x inverse [j][x] 8192
#define OFF_TIS  52977664
#define OFF_IYC  52985856   // y inverse [k][y] 4096
#define OFF_IYS  52989952
#define OFF_WHI  52994048   // fc1 hi-bf16 frags [nt16][lane64][4 uints] = 4096
#define OFF_WLO  52998144   // fc1 lo-bf16 frags = 4096
#define OFF_YAH  53002240   // ydft table A-frags hi [mt2][kt8][lane64][4u] = 4096
#define OFF_YAL  53006336   // ydft table A-frags lo = 4096
#define OFF_XBH  53010432   // xdft table B-frags hi [tab3][jh2][kt8][l64][4u] = 12288
#define OFF_XBL  53022720   // xdft table B-frags lo = 12288
#define OFF_M2H  53035008   // mlp2 A-frags hi [blk6][mt2][lane64][4u] = 3072
#define OFF_M2L  53038080
#define OFF_WWH  53041152   // ww A-frags hi = 3072
#define OFF_WWL  53044224
// total 53047296 floats ~= 202.4 MiB

typedef short bf16x8 __attribute__((ext_vector_type(8)));
typedef float f32x4 __attribute__((ext_vector_type(4)));

__device__ __forceinline__ unsigned short bf16_rne(float f){
    union { float f; unsigned int u; } x; x.f = f;
    unsigned int u = x.u + 0x7fffu + ((x.u>>16)&1u);
    return (unsigned short)(u>>16);
}
__device__ __forceinline__ float bf16_tof(unsigned short h){
    union { unsigned int u; float f; } x; x.u = ((unsigned int)h)<<16;
    return x.f;
}

// Fast exact-erf gelu: A&S 7.1.26, |erf err| <= 1.5e-7. Native rcp+exp.
__device__ __forceinline__ float gelu_f(float x){
    float z = fabsf(x) * 0.70710678118654752f;
    float t = __builtin_amdgcn_rcpf(1.0f + 0.3275911f*z);
    float poly = t*(0.254829592f + t*(-0.284496736f + t*(1.421413741f + t*(-1.453152027f + t*1.061405429f))));
    float e = __expf(-z*z);
    float erf_abs = 1.0f - poly*e;
    float ph = (x >= 0.0f) ? (1.0f + erf_abs) : (1.0f - erf_abs);
    return 0.5f * x * ph;
}

// ---- DFT tables + fc1 / ydft / xdft / mlp2 / ww bf16 fragment packing ----
__global__ void k_tables(float* ws, const float* __restrict__ fc1w,
                         const float* __restrict__ m2w, const float* __restrict__ wwv){
    const double PI = 3.14159265358979323846;
    int t = blockIdx.x*256 + threadIdx.x; // 8192 threads
    if (t < 8192){
        // inverse x-DFT, [j][x]: e^{+i 2pi kx x /256}
        int j2 = t>>8, x2 = t&255;
        int kx2 = (j2<16) ? j2 : (224+j2);
        int p2 = (kx2*x2)&255;
        double a2 = (double)p2*(PI/128.0);
        ws[OFF_TIC+t] = (float)cos(a2);
        ws[OFF_TIS+t] = (float)sin(a2);
    }
    if (t < 4096){
        // y-irfft basis [k][y], scale 1/65536 folds both ifft normalizations
        int k = t>>8, y = t&255;
        int p = (k*y)&255;
        double a = (double)p*(PI/128.0);
        float sc = 1.0f/65536.0f;
        ws[OFF_IYC+t] = (k==0 ? 1.0f : 2.0f*(float)cos(a))*sc;
        ws[OFF_IYS+t] = (k==0 ? 0.0f : -2.0f*(float)sin(a))*sc;
    }
    if (t < 1024){
        // fc1 weight fragments: o = nt*16 + (l&15), c = (l>>4)*8..+7
        int nt = t>>6, l = t&63;
        int o = nt*16 + (l&15), c0 = (l>>4)*8;
        unsigned int hw[4], lw[4];
        #pragma unroll
        for (int e2=0; e2<4; e2++){
            float f0 = fc1w[(c0+2*e2  )*256 + o];
            float f1 = fc1w[(c0+2*e2+1)*256 + o];
            unsigned short h0 = bf16_rne(f0), h1 = bf16_rne(f1);
            unsigned short l0 = bf16_rne(f0 - bf16_tof(h0));
            unsigned short l1 = bf16_rne(f1 - bf16_tof(h1));
            hw[e2] = (unsigned int)h0 | ((unsigned int)h1<<16);
            lw[e2] = (unsigned int)l0 | ((unsigned int)l1<<16);
        }
        unsigned int* whi = (unsigned int*)(ws+OFF_WHI);
        unsigned int* wlo = (unsigned int*)(ws+OFF_WLO);
        #pragma unroll
        for (int e2=0; e2<4; e2++){
            whi[t*4+e2] = hw[e2];
            wlo[t*4+e2] = lw[e2];
        }
    }
    if (t < 1024){
        // ydft A-fragments: t = mt*512 + kt*64 + l
        int mt = t>>9, kt = (t>>6)&7, l = t&63;
        int ky = l&15;
        unsigned int* yah = (unsigned int*)(ws+OFF_YAH);
        unsigned int* yal = (unsigned int*)(ws+OFF_YAL);
        #pragma unroll
        for (int e2=0; e2<4; e2++){
            int y0 = kt*32 + (l>>4)*8 + 2*e2;
            double a0 = (double)((ky*y0)&255)*(PI/128.0);
            double a1 = (double)((ky*(y0+1))&255)*(PI/128.0);
            float v0 = (mt==0) ? (float)cos(a0) : -(float)sin(a0);
            float v1 = (mt==0) ? (float)cos(a1) : -(float)sin(a1);
            unsigned short h0 = bf16_rne(v0), h1 = bf16_rne(v1);
            unsigned short s0 = bf16_rne(v0 - bf16_tof(h0));
            unsigned short s1 = bf16_rne(v1 - bf16_tof(h1));
            yah[t*4+e2] = (unsigned int)h0 | ((unsigned int)h1<<16);
            yal[t*4+e2] = (unsigned int)s0 | ((unsigned int)s1<<16);
        }
    }
    if (t < 3072){
        // xdft B-fragments: t = tab*1024 + jh*512 + kt*64 + l
        int tab = t>>10, jh = (t>>9)&1, kt = (t>>6)&7, l = t&63;
        int j = jh*16 + (l&15);
        int kx = (j<16) ? j : (224+j);
        unsigned int* xbh = (unsigned int*)(ws+OFF_XBH);
        unsigned int* xbl = (unsigned int*)(ws+OFF_XBL);
        #pragma unroll
        for (int e2=0; e2<4; e2++){
            int x0 = kt*32 + (l>>4)*8 + 2*e2;
            double a0 = (double)((kx*x0)&255)*(PI/128.0);
            double a1 = (double)((kx*(x0+1))&255)*(PI/128.0);
            float v0, v1;
            if (tab==0){ v0=(float)cos(a0); v1=(float)cos(a1); }
            else if (tab==1){ v0=-(float)sin(a0); v1=-(float)sin(a1); }
            else { v0=(float)sin(a0); v1=(float)sin(a1); }
            unsigned short h0 = bf16_rne(v0), h1 = bf16_rne(v1);
            unsigned short s0 = bf16_rne(v0 - bf16_tof(h0));
            unsigned short s1 = bf16_rne(v1 - bf16_tof(h1));
            xbh[t*4+e2] = (unsigned int)h0 | ((unsigned int)h1<<16);
            xbl[t*4+e2] = (unsigned int)s0 | ((unsigned int)s1<<16);
        }
    }
    if (t < 768){
        // mlp2 weight A-frags: t = blk*128 + mt*64 + l; o = mt*16+(l&15), c=(l>>4)*8..
        int blk = t>>7, rem = t&127, mt = rem>>6, l = rem&63;
        int o = mt*16 + (l&15), c0 = (l>>4)*8;
        const float* src = m2w + blk*1024;
        unsigned int* mh = (unsigned int*)(ws+OFF_M2H);
        unsigned int* ml = (unsigned int*)(ws+OFF_M2L);
        #pragma unroll
        for (int e2=0; e2<4; e2++){
            float f0 = src[o*32 + c0+2*e2];
            float f1 = src[o*32 + c0+2*e2+1];
            unsigned short h0 = bf16_rne(f0), h1 = bf16_rne(f1);
            unsigned short s0 = bf16_rne(f0 - bf16_tof(h0));
            unsigned short s1 = bf16_rne(f1 - bf16_tof(h1));
            mh[t*4+e2] = (unsigned int)h0 | ((unsigned int)h1<<16);
            ml[t*4+e2] = (unsigned int)s0 | ((unsigned int)s1<<16);
        }
    }
    if (t >= 768 && t < 1536){
        int t2 = t - 768;
        int blk = t2>>7, rem = t2&127, mt = rem>>6, l = rem&63;
        int o = mt*16 + (l&15), c0 = (l>>4)*8;
        const float* src = wwv + blk*1024;
        unsigned int* mh = (unsigned int*)(ws+OFF_WWH);
        unsigned int* ml = (unsigned int*)(ws+OFF_WWL);
        #pragma unroll
        for (int e2=0; e2<4; e2++){
            float f0 = src[o*32 + c0+2*e2];
            float f1 = src[o*32 + c0+2*e2+1];
            unsigned short h0 = bf16_rne(f0), h1 = bf16_rne(f1);
            unsigned short s0 = bf16_rne(f0 - bf16_tof(h0));
            unsigned short s1 = bf16_rne(f1 - bf16_tof(h1));
            mh[t2*4+e2] = (unsigned int)h0 | ((unsigned int)h1<<16);
            ml[t2*4+e2] = (unsigned int)s0 | ((unsigned int)s1<<16);
        }
    }
}

// ---- fc0 + grid concat + transpose to (B,W,V,S,S) ----
__global__ void k_fc0(const float* __restrict__ x, const float* __restrict__ w,
                      const float* __restrict__ bias, float* __restrict__ h0){
    int plane = blockIdx.x>>8, xr = blockIdx.x&255, y = threadIdx.x;
    int xy = xr*256+y;
    long p = (long)plane*NPLANE + xy;
    float f[12];
    #pragma unroll
    for (int i=0;i<10;i++) f[i]=x[p*10+i];
    f[10] = 9.5f + xr*(1.0f/255.0f);
    f[11] = -0.5f + y*(1.0f/255.0f);
    float acc[32];
    #pragma unroll
    for (int o=0;o<32;o++) acc[o]=bias[o];
    #pragma unroll
    for (int c=0;c<12;c++){
        float fv=f[c];
        #pragma unroll
        for (int o=0;o<32;o++) acc[o]+=fv*w[c*32+o];
    }
    int b=plane>>1, v=plane&1;
    int base = b*(kW*CHS) + v*NPLANE + xy;
    #pragma unroll
    for (int o=0;o<32;o++) h0[base + o*CHS]=acc[o];
}

// ---- FUSED forward FFT: ydft (MFMA) -> LDS -> xdft (MFMA) ----
// grid: 256 blocks = bwv; 512 threads = 8 waves.
__global__ __launch_bounds__(512) void k_fwdfft(const float* __restrict__ h,
        const unsigned int* __restrict__ yah, const unsigned int* __restrict__ yal,
        const unsigned int* __restrict__ xbh, const unsigned int* __restrict__ xbl,
        float* __restrict__ fxr, float* __restrict__ fxi){
    __shared__ float fyrl[16*260], fyil[16*260];
    int bwv = blockIdx.x;
    int tid = threadIdx.x;
    int wv = tid>>6, l = tid&63;

    for (int half=0; half<2; ++half){
        int nt = wv*2 + half;            // 0..15
        int x = nt*16 + (l&15);
        int klo = (l>>4)*8;
        const float* hp = h + bwv*NPLANE + x*256 + klo;
        f32x4 accR = {0.f,0.f,0.f,0.f}, accI = {0.f,0.f,0.f,0.f};
        for (int kt=0; kt<8; ++kt){
            float4 b0 = *reinterpret_cast<const float4*>(hp + kt*32);
            float4 b1 = *reinterpret_cast<const float4*>(hp + kt*32 + 4);
            float bv[8] = {b0.x,b0.y,b0.z,b0.w,b1.x,b1.y,b1.z,b1.w};
            bf16x8 bh, bl;
            #pragma unroll
            for (int e=0;e<8;e++){
                unsigned short hb = bf16_rne(bv[e]);
                bh[e] = (short)hb;
                bl[e] = (short)bf16_rne(bv[e] - bf16_tof(hb));
            }
            uint4 a0h = *reinterpret_cast<const uint4*>(&yah[(kt*64+l)*4]);
            uint4 a0l = *reinterpret_cast<const uint4*>(&yal[(kt*64+l)*4]);
            uint4 a1h = *reinterpret_cast<const uint4*>(&yah[(512 + kt*64 + l)*4]);
            uint4 a1l = *reinterpret_cast<const uint4*>(&yal[(512 + kt*64 + l)*4]);
            bf16x8 AH0 = __builtin_bit_cast(bf16x8, a0h);
            bf16x8 AL0 = __builtin_bit_cast(bf16x8, a0l);
            bf16x8 AH1 = __builtin_bit_cast(bf16x8, a1h);
            bf16x8 AL1 = __builtin_bit_cast(bf16x8, a1l);
            accR = __builtin_amdgcn_mfma_f32_16x16x32_bf16(AH0, bh, accR, 0,0,0);
            accR = __builtin_amdgcn_mfma_f32_16x16x32_bf16(AH0, bl, accR, 0,0,0);
            accR = __builtin_amdgcn_mfma_f32_16x16x32_bf16(AL0, bh, accR, 0,0,0);
            accI = __builtin_amdgcn_mfma_f32_16x16x32_bf16(AH1, bh, accI, 0,0,0);
            accI = __builtin_amdgcn_mfma_f32_16x16x32_bf16(AH1, bl, accI, 0,0,0);
            accI = __builtin_amdgcn_mfma_f32_16x16x32_bf16(AL1, bh, accI, 0,0,0);
        }
        int ky0 = (l>>4)*4;
        #pragma unroll
        for (int r=0;r<4;r++){
            fyrl[(ky0+r)*260 + x] = accR[r];
            fyil[(ky0+r)*260 + x] = accI[r];
        }
    }
    __syncthreads();

    if (wv < 2){
        int jh = wv;
        const float* ar = fyrl + (l&15)*260 + (l>>4)*8;
        const float* ai = fyil + (l&15)*260 + (l>>4)*8;
        f32x4 accR = {0.f,0.f,0.f,0.f}, accI = {0.f,0.f,0.f,0.f};
        for (int kt=0; kt<8; ++kt){
            float4 r0 = *reinterpret_cast<const float4*>(ar + kt*32);
            float4 r1 = *reinterpret_cast<const float4*>(ar + kt*32 + 4);
            float4 i0 = *reinterpret_cast<const float4*>(ai + kt*32);
            float4 i1 = *reinterpret_cast<const float4*>(ai + kt*32 + 4);
            float rv[8] = {r0.x,r0.y,r0.z,r0.w,r1.x,r1.y,r1.z,r1.w};
            float iv[8] = {i0.x,i0.y,i0.z,i0.w,i1.x,i1.y,i1.z,i1.w};
            bf16x8 Rh, Rl, Ih, Il;
            #pragma unroll
            for (int e=0;e<8;e++){
                unsigned short hb = bf16_rne(rv[e]);
                Rh[e] = (short)hb;
                Rl[e] = (short)bf16_rne(rv[e] - bf16_tof(hb));
                unsigned short hb2 = bf16_rne(iv[e]);
                Ih[e] = (short)hb2;
                Il[e] = (short)bf16_rne(iv[e] - bf16_tof(hb2));
            }
            int fb = (jh*512 + kt*64 + l)*4;   // tab stride = 1024 frags * 4
            uint4 ch = *reinterpret_cast<const uint4*>(&xbh[fb]);
            uint4 cl = *reinterpret_cast<const uint4*>(&xbl[fb]);
            uint4 sh = *reinterpret_cast<const uint4*>(&xbh[fb + 4096]);
            uint4 sl = *reinterpret_cast<const uint4*>(&xbl[fb + 4096]);
            uint4 ph = *reinterpret_cast<const uint4*>(&xbh[fb + 8192]);
            uint4 pl = *reinterpret_cast<const uint4*>(&xbl[fb + 8192]);
            bf16x8 CH = __builtin_bit_cast(bf16x8, ch);
            bf16x8 CL = __builtin_bit_cast(bf16x8, cl);
            bf16x8 SH = __builtin_bit_cast(bf16x8, sh);
            bf16x8 SL = __builtin_bit_cast(bf16x8, sl);
            bf16x8 PH = __builtin_bit_cast(bf16x8, ph);
            bf16x8 PL = __builtin_bit_cast(bf16x8, pl);
            accR = __builtin_amdgcn_mfma_f32_16x16x32_bf16(Rh, CH, accR, 0,0,0);
            accR = __builtin_amdgcn_mfma_f32_16x16x32_bf16(Rh, CL, accR, 0,0,0);
            accR = __builtin_amdgcn_mfma_f32_16x16x32_bf16(Rl, CH, accR, 0,0,0);
            accR = __builtin_amdgcn_mfma_f32_16x16x32_bf16(Ih, PH, accR, 0,0,0);
            accR = __builtin_amdgcn_mfma_f32_16x16x32_bf16(Ih, PL, accR, 0,0,0);
            accR = __builtin_amdgcn_mfma_f32_16x16x32_bf16(Il, PH, accR, 0,0,0);
            accI = __builtin_amdgcn_mfma_f32_16x16x32_bf16(Rh, SH, accI, 0,0,0);
            accI = __builtin_amdgcn_mfma_f32_16x16x32_bf16(Rh, SL, accI, 0,0,0);
            accI = __builtin_amdgcn_mfma_f32_16x16x32_bf16(Rl, SH, accI, 0,0,0);
            accI = __builtin_amdgcn_mfma_f32_16x16x32_bf16(Ih, CH, accI, 0,0,0);
            accI = __builtin_amdgcn_mfma_f32_16x16x32_bf16(Ih, CL, accI, 0,0,0);
            accI = __builtin_amdgcn_mfma_f32_16x16x32_bf16(Il, CH, accI, 0,0,0);
        }
        int ob = bwv*512 + jh*16 + (l&15);
        int ky0 = (l>>4)*4;
        #pragma unroll
        for (int r=0;r<4;r++){
            fxr[ob + (ky0+r)*32] = accR[r];
            fxi[ob + (ky0+r)*32] = accI[r];
        }
    }
}

// ---- complex mode mixing (w1/w2) with mlp1 fused via LDS ----
// grid: 256 blocks = (b4, v2, ky16, jh2); 512 threads = (o32, j16)
__global__ void k_modemix(const float* __restrict__ fxr, const float* __restrict__ fxi,
                          const float* __restrict__ w1r_, const float* __restrict__ w1i_,
                          const float* __restrict__ w2r_, const float* __restrict__ w2i_,
                          const float* __restrict__ m1, float* __restrict__ g2r, float* __restrict__ g2i){
    __shared__ float glr[32*17], gli[32*17];
    int blk = blockIdx.x;
    int jh = blk&1, ky = (blk>>1)&15, v = (blk>>5)&1, b = blk>>6;
    int o = threadIdx.x>>4, jl = threadIdx.x&15;
    int j = jh*16 + jl;
    int kxi = (j<16) ? j : (j-16);
    const float* wr_ = (j<16) ? w1r_ : w2r_;
    const float* wi_ = (j<16) ? w1i_ : w2i_;
    int wbase = (o*kV + v)*256 + kxi*16 + ky;         // + i*16384
    int fbase = (b*kW*kV + v)*512 + ky*32 + j;        // + i*1024
    float re=0.f, im=0.f;
    #pragma unroll 8
    for (int i=0;i<32;i++){
        float fr=fxr[fbase+i*1024], fi=fxi[fbase+i*1024];
        float wr=wr_[wbase+i*16384], wi=wi_[wbase+i*16384];
        re += fr*wr - fi*wi;
        im += fr*wi + fi*wr;
    }
    glr[o*17+jl]=re; gli[o*17+jl]=im;
    __syncthreads();
    // mlp1: g2[o] = sum_i m1[o][i] * g[i]   (same-j mixing only)
    float r2=0.f, i2=0.f;
    #pragma unroll 8
    for (int i=0;i<32;i++){
        float m = m1[o*32+i];
        r2 += m*glr[i*17+jl];
        i2 += m*gli[i*17+jl];
    }
    int gid = ((b*kW + o)*kV + v)*512 + ky*32 + j;
    g2r[gid]=r2; g2i[gid]=i2;
}

// ---- FUSED inverse + pointwise, MFMA phase 2b ----
// grid: 2048 blocks = (b4, v2, xr256); 256 threads = 4 waves.
// Phase 1: x-iDFT -> frl/fil. Phase 2a: y-irfft + mlp1b + gelu -> tl[c][y].
// Phase 2b (MFMA): out[o][y] = gelu(m2·t + ww·h + base) (+res).
//   A = weights {m=o=l&15 (+mt*16), k=c=(l>>4)*8+e} (packed frags),
//   B = data {n=y=l&15 (+tile), k=c} (t from LDS, h global, split hi/lo),
//   D {row=o-quad, col=y} — k_head-validated mapping. Constant-bound loops
//   fully unrolled (R7/R8/R14 rule). In-place safe: per-tile B-frags read
//   before stores; waves own disjoint y.
__global__ void k_invpoint(const float* __restrict__ g2r, const float* __restrict__ g2i,
                           const float* __restrict__ xic, const float* __restrict__ xis,
                           const float* __restrict__ iyc, const float* __restrict__ iys,
                           const float* __restrict__ b1,
                           const float* h, const float* res, float* out,
                           const unsigned int* __restrict__ m2h, const unsigned int* __restrict__ m2l,
                           const unsigned int* __restrict__ wwh, const unsigned int* __restrict__ wwl,
                           const float* __restrict__ b2,
                           const float* __restrict__ wb_, const float* __restrict__ bw_,
                           const float* __restrict__ bb_){
    __shared__ float frl[16*36], fil[16*36];   // [k][o] pad 36
    __shared__ float tl[32*260];               // [c][y] pad 260
    __shared__ float cinit[32], bwy_[32];
    int tid = threadIdx.x;
    int blk = blockIdx.x;
    int b = blk>>9, v = (blk>>8)&1, xr = blk&255;
    float gx = 9.5f + xr*(1.0f/255.0f);
    if (tid < 32){
        cinit[tid] = b2[tid] + wb_[tid] + bb_[tid] + bw_[tid*2]*gx;
        bwy_[tid] = bw_[tid*2+1];
    }

    // ---- phase 1: x-iDFT at fixed x=xr ----
    #pragma unroll
    for (int pp=0; pp<2; pp++){
        int p = tid + pp*256;
        int o = p>>4, k = p&15;
        const float* gr_ = g2r + (((b*kW + o)*kV + v)<<9) + k*32;
        const float* gi_ = g2i + (((b*kW + o)*kV + v)<<9) + k*32;
        float re=0.f, im=0.f;
        #pragma unroll 8
        for (int j=0;j<32;j++){
            float grv=gr_[j], giv=gi_[j];
            float c=xic[j*256+xr], s=xis[j*256+xr];
            re += grv*c - giv*s;
            im += grv*s + giv*c;
        }
        frl[k*36+o]=re; fil[k*36+o]=im;
    }
    __syncthreads();

    // ---- phase 2a: y-irfft, 4o x 8y tile; t = gelu(acc + b1) -> tl[c][y] ----
    {
        int og = tid&7, yg = tid>>3;
        int o0 = og*4, y0 = yg*8;
        float acc[4][8];
        #pragma unroll
        for (int oo=0;oo<4;oo++){
            float bb1 = b1[o0+oo];
            #pragma unroll
            for (int yy=0;yy<8;yy++) acc[oo][yy]=bb1;
        }
        #pragma unroll 4
        for (int k=0;k<16;k++){
            float4 yc0 = *reinterpret_cast<const float4*>(&iyc[k*256+y0]);
            float4 yc1 = *reinterpret_cast<const float4*>(&iyc[k*256+y0+4]);
            float4 ys0 = *reinterpret_cast<const float4*>(&iys[k*256+y0]);
            float4 ys1 = *reinterpret_cast<const float4*>(&iys[k*256+y0+4]);
            float4 fr4 = *reinterpret_cast<const float4*>(&frl[k*36+o0]);
            float4 fi4 = *reinterpret_cast<const float4*>(&fil[k*36+o0]);
            float frv[4]={fr4.x,fr4.y,fr4.z,fr4.w};
            float fiv[4]={fi4.x,fi4.y,fi4.z,fi4.w};
            #pragma unroll
            for (int oo=0;oo<4;oo++){
                acc[oo][0] += frv[oo]*yc0.x + fiv[oo]*ys0.x;
                acc[oo][1] += frv[oo]*yc0.y + fiv[oo]*ys0.y;
                acc[oo][2] += frv[oo]*yc0.z + fiv[oo]*ys0.z;
                acc[oo][3] += frv[oo]*yc0.w + fiv[oo]*ys0.w;
                acc[oo][4] += frv[oo]*yc1.x + fiv[oo]*ys1.x;
                acc[oo][5] += frv[oo]*yc1.y + fiv[oo]*ys1.y;
                acc[oo][6] += frv[oo]*yc1.z + fiv[oo]*ys1.z;
                acc[oo][7] += frv[oo]*yc1.w + fiv[oo]*ys1.w;
            }
        }
        #pragma unroll
        for (int oo=0;oo<4;oo++){
            float4 w0, w1;
            w0.x = gelu_f(acc[oo][0]); w0.y = gelu_f(acc[oo][1]);
            w0.z = gelu_f(acc[oo][2]); w0.w = gelu_f(acc[oo][3]);
            w1.x = gelu_f(acc[oo][4]); w1.y = gelu_f(acc[oo][5]);
            w1.z = gelu_f(acc[oo][6]); w1.w = gelu_f(acc[oo][7]);
            *reinterpret_cast<float4*>(&tl[(o0+oo)*260 + y0])   = w0;
            *reinterpret_cast<float4*>(&tl[(o0+oo)*260 + y0+4]) = w1;
        }
    }
    __syncthreads();

    // ---- phase 2b: MFMA mlp2(t) + ww(h) + base, gelu, +res ----
    int wv = tid>>6, l = tid&63;
    int lm = l&15, lg = l>>4;
    int pb = b*(kW*CHS) + v*NPLANE + xr*256;
    // weight A-frags for 2 o-tiles (hoisted: 8 uint4 = 32 VGPR)
    bf16x8 M2Hf[2], M2Lf[2], WWHf[2], WWLf[2];
    #pragma unroll
    for (int mt=0; mt<2; ++mt){
        M2Hf[mt] = __builtin_bit_cast(bf16x8, *reinterpret_cast<const uint4*>(&m2h[(mt*64+l)*4]));
        M2Lf[mt] = __builtin_bit_cast(bf16x8, *reinterpret_cast<const uint4*>(&m2l[(mt*64+l)*4]));
        WWHf[mt] = __builtin_bit_cast(bf16x8, *reinterpret_cast<const uint4*>(&wwh[(mt*64+l)*4]));
        WWLf[mt] = __builtin_bit_cast(bf16x8, *reinterpret_cast<const uint4*>(&wwl[(mt*64+l)*4]));
    }
    for (int nt=0; nt<4; ++nt){
        int y0 = wv*64 + nt*16;
        int yy = y0 + lm;
        float gyv = -0.5f + yy*(1.0f/255.0f);
        // B-frags: t from LDS, h from global; split hi/lo
        bf16x8 th, tlw, hh, hlw;
        #pragma unroll
        for (int e=0;e<8;e++){
            float tvv = tl[(lg*8+e)*260 + yy];
            unsigned short tb = bf16_rne(tvv);
            th[e] = (short)tb;
            tlw[e] = (short)bf16_rne(tvv - bf16_tof(tb));
            float hvv = h[pb + (lg*8+e)*CHS + yy];
            unsigned short hb = bf16_rne(hvv);
            hh[e] = (short)hb;
            hlw[e] = (short)bf16_rne(hvv - bf16_tof(hb));
        }
        for (int mt=0; mt<2; ++mt){
            f32x4 d = {0.f,0.f,0.f,0.f};
            d = __builtin_amdgcn_mfma_f32_16x16x32_bf16(M2Hf[mt], th,  d, 0,0,0);
            d = __builtin_amdgcn_mfma_f32_16x16x32_bf16(M2Hf[mt], tlw, d, 0,0,0);
            d = __builtin_amdgcn_mfma_f32_16x16x32_bf16(M2Lf[mt], th,  d, 0,0,0);
            d = __builtin_amdgcn_mfma_f32_16x16x32_bf16(WWHf[mt], hh,  d, 0,0,0);
            d = __builtin_amdgcn_mfma_f32_16x16x32_bf16(WWHf[mt], hlw, d, 0,0,0);
            d = __builtin_amdgcn_mfma_f32_16x16x32_bf16(WWLf[mt], hh,  d, 0,0,0);
            #pragma unroll
            for (int r=0;r<4;r++){
                int o = mt*16 + lg*4 + r;
                float val = gelu_f(d[r] + cinit[o] + bwy_[o]*gyv);
                int addr = pb + o*CHS + yy;
                if (res) val += res[addr];
                out[addr] = val;
            }
        }
    }
}

// ---- head via MFMA: LDS-staged h tile, fc1 (hi + weight-lo) + gelu + fc2 ----
// grid: 2048 blocks x 256 thr. RULE (3x: R7/R8/R14): MFMA bodies w/ fresh acc
// + loop-invariant A-frags must be FULLY unrolled w/ constant bounds.
__global__ __launch_bounds__(256) void k_head(const float* __restrict__ h,
        const unsigned int* __restrict__ whi, const unsigned int* __restrict__ wlo,
        const float* __restrict__ fc1b, const float* __restrict__ fc2w,
        const float* __restrict__ fc2b, float* __restrict__ out){
    __shared__ float hl[32*257];   // pad 257: all 64 lanes distinct banks (2-way = free)
    int tid = threadIdx.x;
    int plane = blockIdx.x>>8, xr = blockIdx.x&255;
    int b = plane>>1, v = plane&1;
    const float* hp = h + b*(kW*CHS) + v*NPLANE + xr*256;
    #pragma unroll 8
    for (int c=0;c<32;c++) hl[c*257 + tid] = hp[c*CHS + tid];  // coalesced 1KB/instr
    __syncthreads();

    int wv = tid>>6, l = tid&63;
    int lm = l&15, lg = l>>4;
    float f2b[5];
    #pragma unroll
    for (int j=0;j<5;j++) f2b[j] = fc2b[j];

    for (int mt=0; mt<4; ++mt){
        int pxl = wv*64 + mt*16 + lm;    // local pixel for A row
        bf16x8 ah;
        #pragma unroll
        for (int e=0;e<8;e++){
            float a = hl[(lg*8+e)*257 + pxl];
            ah[e] = (short)bf16_rne(a);
        }
        float fj[4][5];
        #pragma unroll
        for (int r=0;r<4;r++)
            #pragma unroll
            for (int j=0;j<5;j++) fj[r][j]=0.f;
        for (int q=0; q<4; ++q){
            #pragma unroll
            for (int ntq=0; ntq<4; ntq++){
                int nt = q*4 + ntq;
                uint4 rh = *reinterpret_cast<const uint4*>(&whi[(nt*64+l)*4]);
                uint4 rl = *reinterpret_cast<const uint4*>(&wlo[(nt*64+l)*4]);
                bf16x8 BH = __builtin_bit_cast(bf16x8, rh);
                bf16x8 BL = __builtin_bit_cast(bf16x8, rl);
                f32x4 d = {0.f,0.f,0.f,0.f};
                d = __builtin_amdgcn_mfma_f32_16x16x32_bf16(ah, BH, d, 0,0,0);
                d = __builtin_amdgcn_mfma_f32_16x16x32_bf16(ah, BL, d, 0,0,0);
                int o = nt*16 + lm;
                float b1  = fc1b[o];
                float w20 = fc2w[o*5+0], w21 = fc2w[o*5+1], w22 = fc2w[o*5+2];
                float w23 = fc2w[o*5+3], w24 = fc2w[o*5+4];
                #pragma unroll
                for (int r=0;r<4;r++){
                    float u = gelu_f(d[r] + b1);
                    fj[r][0] += u*w20; fj[r][1] += u*w21; fj[r][2] += u*w22;
                    fj[r][3] += u*w23; fj[r][4] += u*w24;
                }
            }
        }
        // reduce over the 16 o-lanes (lm bits)
        #pragma unroll
        for (int m=1; m<16; m<<=1){
            #pragma unroll
            for (int r=0;r<4;r++){
                #pragma unroll
                for (int j=0;j<5;j++) fj[r][j] += __shfl_xor(fj[r][j], m, 64);
            }
        }
        if (lm == 0){
            int prow = blockIdx.x*256 + wv*64 + mt*16 + lg*4;  // D rows m = lg*4+r
            #pragma unroll
            for (int r=0;r<4;r++){
                long ob = (long)(prow+r)*5;
                #pragma unroll
                for (int j=0;j<5;j++) out[ob+j] = fj[r][j] + f2b[j];
            }
        }
    }
}

extern "C" void kernel_launch(void* const* d_in, const int* in_sizes, int n_in,
                              void* d_out, int out_size, void* d_ws, size_t ws_size,
                              hipStream_t stream){
    const float* x    =(const float*)d_in[0];
    const float* fc0w =(const float*)d_in[1];
    const float* fc0b =(const float*)d_in[2];
    const float* w1r  =(const float*)d_in[3];
    const float* w1i  =(const float*)d_in[4];
    const float* w2r  =(const float*)d_in[5];
    const float* w2i  =(const float*)d_in[6];
    const float* m1w  =(const float*)d_in[7];
    const float* m1b  =(const float*)d_in[8];
    const float* m2w  =(const float*)d_in[9];
    const float* m2b  =(const float*)d_in[10];
    const float* ww   =(const float*)d_in[11];
    const float* wb   =(const float*)d_in[12];
    const float* bw   =(const float*)d_in[13];
    const float* bb   =(const float*)d_in[14];
    const float* fc1w =(const float*)d_in[15];
    const float* fc1b =(const float*)d_in[16];
    const float* fc2w =(const float*)d_in[17];
    const float* fc2b =(const float*)d_in[18];

    float* ws = (float*)d_ws;
    float* big[3] = {ws+OFF_BIG0, ws+OFF_BIG1, ws+OFF_BIG2};
    float* fxr = ws+OFF_FXR; float* fxi = ws+OFF_FXI;
    float* gr  = ws+OFF_GR;  float* gi  = ws+OFF_GI;

    k_tables<<<32,256,0,stream>>>(ws, fc1w, m2w, ww);
    k_fc0<<<2048,256,0,stream>>>(x, fc0w, fc0b, big[0]);

    // schedule: {in, out, res}
    const int s_in [6] = {0,0,2,2,2,0};
    const int s_out[6] = {0,2,2,2,0,0};
    const int s_res[6] = {-1,-1,0,-1,-1,2};

    for (int blk=0; blk<6; ++blk){
        float* in   = big[s_in[blk]];
        float* outb = big[s_out[blk]];
        const float* resp = (s_res[blk] < 0) ? nullptr : big[s_res[blk]];
        k_fwdfft<<<256,512,0,stream>>>(in,
            (const unsigned int*)(ws+OFF_YAH), (const unsigned int*)(ws+OFF_YAL),
            (const unsigned int*)(ws+OFF_XBH), (const unsigned int*)(ws+OFF_XBL),
            fxr, fxi);
        k_modemix<<<256,512,0,stream>>>(fxr, fxi,
            w1r+blk*524288, w1i+blk*524288, w2r+blk*524288, w2i+blk*524288,
            m1w+blk*1024, gr, gi);
        k_invpoint<<<2048,256,0,stream>>>(gr, gi, ws+OFF_TIC, ws+OFF_TIS,
            ws+OFF_IYC, ws+OFF_IYS, m1b+blk*32,
            in, resp, outb,
            (const unsigned int*)(ws+OFF_M2H) + blk*512,
            (const unsigned int*)(ws+OFF_M2L) + blk*512,
            (const unsigned int*)(ws+OFF_WWH) + blk*512,
            (const unsigned int*)(ws+OFF_WWL) + blk*512,
            m2b+blk*32, wb+blk*32, bw+blk*64, bb+blk*32);
    }
    k_head<<<2048,256,0,stream>>>(big[0],
        (const unsigned int*)(ws+OFF_WHI), (const unsigned int*)(ws+OFF_WLO),
        fc1b, fc2w, fc2b, (float*)d_out);
}

// Round 20
// 935.939 us; speedup vs baseline: 1.3320x; 1.0697x over previous
//
#include <hip/hip_runtime.h>

// ---- problem constants ----
#define kB 4
#define kV 2
#define kS 256
#define kW 32
#define kM 16
#define kNB 6
#define kTIN 10
#define kSTEP 5

#define NPLANE 65536            // S*S
#define NBWV   (kB*kW*kV)       // 256
#define BIGN   (kB*kW*kV*NPLANE)// 16777216 floats per state buffer
#define CHS    (kV*NPLANE)      // channel stride = 131072

// ---- workspace layout (float offsets) ----
// NOTE: big1 (t-buffer) dead since R10 -> reused for repacked modemix weights.
#define OFF_BIG0 0
#define OFF_WPR  16777216   // [blk6][v2][ky16][j32][i32][o32] = 6291456
#define OFF_WPI  23068672
#define OFF_BIG2 33554432
#define OFF_FXR  52428800   // [bwv][ky16][j32] = 131072
#define OFF_FXI  52559872
#define OFF_GR   52690944
#define OFF_GI   52822016
#define OFF_TIC  52969472   // x inverse [j][x] 8192
#define OFF_TIS  52977664
#define OFF_IYC  52985856   // y inverse [k][y] 4096
#define OFF_IYS  52989952
#define OFF_WHI  52994048   // fc1 hi-bf16 frags [nt16][lane64][4 uints] = 4096
#define OFF_WLO  52998144   // fc1 lo-bf16 frags = 4096
#define OFF_YAH  53002240   // ydft table A-frags hi [mt2][kt8][lane64][4u] = 4096
#define OFF_YAL  53006336   // ydft table A-frags lo = 4096
#define OFF_XBH  53010432   // xdft table B-frags hi [tab3][jh2][kt8][l64][4u] = 12288
#define OFF_XBL  53022720   // xdft table B-frags lo = 12288
#define OFF_M2H  53035008   // mlp2 A-frags hi [blk6][mt2][lane64][4u] = 3072
#define OFF_M2L  53038080
#define OFF_WWH  53041152   // ww A-frags hi = 3072
#define OFF_WWL  53044224
// total 53047296 floats ~= 202.4 MiB (unchanged)

typedef short bf16x8 __attribute__((ext_vector_type(8)));
typedef float f32x4 __attribute__((ext_vector_type(4)));

__device__ __forceinline__ unsigned short bf16_rne(float f){
    union { float f; unsigned int u; } x; x.f = f;
    unsigned int u = x.u + 0x7fffu + ((x.u>>16)&1u);
    return (unsigned short)(u>>16);
}
__device__ __forceinline__ float bf16_tof(unsigned short h){
    union { unsigned int u; float f; } x; x.u = ((unsigned int)h)<<16;
    return x.f;
}

// Fast exact-erf gelu: A&S 7.1.26, |erf err| <= 1.5e-7. Native rcp+exp.
__device__ __forceinline__ float gelu_f(float x){
    float z = fabsf(x) * 0.70710678118654752f;
    float t = __builtin_amdgcn_rcpf(1.0f + 0.3275911f*z);
    float poly = t*(0.254829592f + t*(-0.284496736f + t*(1.421413741f + t*(-1.453152027f + t*1.061405429f))));
    float e = __expf(-z*z);
    float erf_abs = 1.0f - poly*e;
    float ph = (x >= 0.0f) ? (1.0f + erf_abs) : (1.0f - erf_abs);
    return 0.5f * x * ph;
}

// ---- DFT tables + fc1 / ydft / xdft / mlp2 / ww bf16 fragment packing ----
__global__ void k_tables(float* ws, const float* __restrict__ fc1w,
                         const float* __restrict__ m2w, const float* __restrict__ wwv){
    const double PI = 3.14159265358979323846;
    int t = blockIdx.x*256 + threadIdx.x; // 8192 threads
    if (t < 8192){
        // inverse x-DFT, [j][x]: e^{+i 2pi kx x /256}
        int j2 = t>>8, x2 = t&255;
        int kx2 = (j2<16) ? j2 : (224+j2);
        int p2 = (kx2*x2)&255;
        double a2 = (double)p2*(PI/128.0);
        ws[OFF_TIC+t] = (float)cos(a2);
        ws[OFF_TIS+t] = (float)sin(a2);
    }
    if (t < 4096){
        // y-irfft basis [k][y], scale 1/65536 folds both ifft normalizations
        int k = t>>8, y = t&255;
        int p = (k*y)&255;
        double a = (double)p*(PI/128.0);
        float sc = 1.0f/65536.0f;
        ws[OFF_IYC+t] = (k==0 ? 1.0f : 2.0f*(float)cos(a))*sc;
        ws[OFF_IYS+t] = (k==0 ? 0.0f : -2.0f*(float)sin(a))*sc;
    }
    if (t < 1024){
        // fc1 weight fragments: o = nt*16 + (l&15), c = (l>>4)*8..+7
        int nt = t>>6, l = t&63;
        int o = nt*16 + (l&15), c0 = (l>>4)*8;
        unsigned int hw[4], lw[4];
        #pragma unroll
        for (int e2=0; e2<4; e2++){
            float f0 = fc1w[(c0+2*e2  )*256 + o];
            float f1 = fc1w[(c0+2*e2+1)*256 + o];
            unsigned short h0 = bf16_rne(f0), h1 = bf16_rne(f1);
            unsigned short l0 = bf16_rne(f0 - bf16_tof(h0));
            unsigned short l1 = bf16_rne(f1 - bf16_tof(h1));
            hw[e2] = (unsigned int)h0 | ((unsigned int)h1<<16);
            lw[e2] = (unsigned int)l0 | ((unsigned int)l1<<16);
        }
        unsigned int* whi = (unsigned int*)(ws+OFF_WHI);
        unsigned int* wlo = (unsigned int*)(ws+OFF_WLO);
        #pragma unroll
        for (int e2=0; e2<4; e2++){
            whi[t*4+e2] = hw[e2];
            wlo[t*4+e2] = lw[e2];
        }
    }
    if (t < 1024){
        // ydft A-fragments: t = mt*512 + kt*64 + l
        int mt = t>>9, kt = (t>>6)&7, l = t&63;
        int ky = l&15;
        unsigned int* yah = (unsigned int*)(ws+OFF_YAH);
        unsigned int* yal = (unsigned int*)(ws+OFF_YAL);
        #pragma unroll
        for (int e2=0; e2<4; e2++){
            int y0 = kt*32 + (l>>4)*8 + 2*e2;
            double a0 = (double)((ky*y0)&255)*(PI/128.0);
            double a1 = (double)((ky*(y0+1))&255)*(PI/128.0);
            float v0 = (mt==0) ? (float)cos(a0) : -(float)sin(a0);
            float v1 = (mt==0) ? (float)cos(a1) : -(float)sin(a1);
            unsigned short h0 = bf16_rne(v0), h1 = bf16_rne(v1);
            unsigned short s0 = bf16_rne(v0 - bf16_tof(h0));
            unsigned short s1 = bf16_rne(v1 - bf16_tof(h1));
            yah[t*4+e2] = (unsigned int)h0 | ((unsigned int)h1<<16);
            yal[t*4+e2] = (unsigned int)s0 | ((unsigned int)s1<<16);
        }
    }
    if (t < 3072){
        // xdft B-fragments: t = tab*1024 + jh*512 + kt*64 + l
        int tab = t>>10, jh = (t>>9)&1, kt = (t>>6)&7, l = t&63;
        int j = jh*16 + (l&15);
        int kx = (j<16) ? j : (224+j);
        unsigned int* xbh = (unsigned int*)(ws+OFF_XBH);
        unsigned int* xbl = (unsigned int*)(ws+OFF_XBL);
        #pragma unroll
        for (int e2=0; e2<4; e2++){
            int x0 = kt*32 + (l>>4)*8 + 2*e2;
            double a0 = (double)((kx*x0)&255)*(PI/128.0);
            double a1 = (double)((kx*(x0+1))&255)*(PI/128.0);
            float v0, v1;
            if (tab==0){ v0=(float)cos(a0); v1=(float)cos(a1); }
            else if (tab==1){ v0=-(float)sin(a0); v1=-(float)sin(a1); }
            else { v0=(float)sin(a0); v1=(float)sin(a1); }
            unsigned short h0 = bf16_rne(v0), h1 = bf16_rne(v1);
            unsigned short s0 = bf16_rne(v0 - bf16_tof(h0));
            unsigned short s1 = bf16_rne(v1 - bf16_tof(h1));
            xbh[t*4+e2] = (unsigned int)h0 | ((unsigned int)h1<<16);
            xbl[t*4+e2] = (unsigned int)s0 | ((unsigned int)s1<<16);
        }
    }
    if (t < 768){
        // mlp2 weight A-frags: t = blk*128 + mt*64 + l; o = mt*16+(l&15), c=(l>>4)*8..
        int blk = t>>7, rem = t&127, mt = rem>>6, l = rem&63;
        int o = mt*16 + (l&15), c0 = (l>>4)*8;
        const float* src = m2w + blk*1024;
        unsigned int* mh = (unsigned int*)(ws+OFF_M2H);
        unsigned int* ml = (unsigned int*)(ws+OFF_M2L);
        #pragma unroll
        for (int e2=0; e2<4; e2++){
            float f0 = src[o*32 + c0+2*e2];
            float f1 = src[o*32 + c0+2*e2+1];
            unsigned short h0 = bf16_rne(f0), h1 = bf16_rne(f1);
            unsigned short s0 = bf16_rne(f0 - bf16_tof(h0));
            unsigned short s1 = bf16_rne(f1 - bf16_tof(h1));
            mh[t*4+e2] = (unsigned int)h0 | ((unsigned int)h1<<16);
            ml[t*4+e2] = (unsigned int)s0 | ((unsigned int)s1<<16);
        }
    }
    if (t >= 768 && t < 1536){
        int t2 = t - 768;
        int blk = t2>>7, rem = t2&127, mt = rem>>6, l = rem&63;
        int o = mt*16 + (l&15), c0 = (l>>4)*8;
        const float* src = wwv + blk*1024;
        unsigned int* mh = (unsigned int*)(ws+OFF_WWH);
        unsigned int* ml = (unsigned int*)(ws+OFF_WWL);
        #pragma unroll
        for (int e2=0; e2<4; e2++){
            float f0 = src[o*32 + c0+2*e2];
            float f1 = src[o*32 + c0+2*e2+1];
            unsigned short h0 = bf16_rne(f0), h1 = bf16_rne(f1);
            unsigned short s0 = bf16_rne(f0 - bf16_tof(h0));
            unsigned short s1 = bf16_rne(f1 - bf16_tof(h1));
            mh[t2*4+e2] = (unsigned int)h0 | ((unsigned int)h1<<16);
            ml[t2*4+e2] = (unsigned int)s0 | ((unsigned int)s1<<16);
        }
    }
}

// ---- weight repack for modemix: wP[blk][v][ky][j][i][o] (coalesced o-runs) ----
// grid: 1536 blocks = (blk6, i32, v2, part2, jh2); 256 threads.
// LDS-tiled transpose: coalesced 1KB reads, 128B write runs.
__global__ void k_wpack(const float* __restrict__ w1r, const float* __restrict__ w1i,
                        const float* __restrict__ w2r, const float* __restrict__ w2i,
                        float* __restrict__ wpr, float* __restrict__ wpi){
    __shared__ float lds[32*272];   // [o][kxi][ky] pad 17
    int bid = blockIdx.x;
    int blk = bid>>8, rem = bid&255;
    int i = rem>>3, v = (rem>>2)&1, part = (rem>>1)&1, jh = rem&1;
    const float* src0 = (part==0) ? (jh==0 ? w1r : w2r) : (jh==0 ? w1i : w2i);
    const float* src = src0 + blk*524288;
    int tid = threadIdx.x;
    // read [o][kxi*16+ky] slices: src[((i*32+o)*2+v)*256 + tid]
    for (int o=0;o<32;o++){
        lds[o*272 + (tid>>4)*17 + (tid&15)] = src[((i*32+o)*2+v)*256 + tid];
    }
    __syncthreads();
    float* dst = ((part==0) ? wpr : wpi);
    int o = tid&31, grp = tid>>5;    // 8 groups x 32 o
    for (int p=0;p<32;p++){
        int pair = p*8 + grp;        // 0..255
        int ky = pair>>4, kxi = pair&15;
        int j = jh*16 + kxi;
        dst[((((blk*2+v)*16+ky)*32 + j)*32 + i)*32 + o] = lds[o*272 + kxi*17 + ky];
    }
}

// ---- fc0 + grid concat + transpose to (B,W,V,S,S) ----
__global__ void k_fc0(const float* __restrict__ x, const float* __restrict__ w,
                      const float* __restrict__ bias, float* __restrict__ h0){
    int plane = blockIdx.x>>8, xr = blockIdx.x&255, y = threadIdx.x;
    int xy = xr*256+y;
    long p = (long)plane*NPLANE + xy;
    float f[12];
    #pragma unroll
    for (int i=0;i<10;i++) f[i]=x[p*10+i];
    f[10] = 9.5f + xr*(1.0f/255.0f);
    f[11] = -0.5f + y*(1.0f/255.0f);
    float acc[32];
    #pragma unroll
    for (int o=0;o<32;o++) acc[o]=bias[o];
    #pragma unroll
    for (int c=0;c<12;c++){
        float fv=f[c];
        #pragma unroll
        for (int o=0;o<32;o++) acc[o]+=fv*w[c*32+o];
    }
    int b=plane>>1, v=plane&1;
    int base = b*(kW*CHS) + v*NPLANE + xy;
    #pragma unroll
    for (int o=0;o<32;o++) h0[base + o*CHS]=acc[o];
}

// ---- FUSED forward FFT: ydft (MFMA) -> LDS -> xdft (MFMA) ----
// grid: 256 blocks = bwv; 512 threads = 8 waves.
__global__ __launch_bounds__(512) void k_fwdfft(const float* __restrict__ h,
        const unsigned int* __restrict__ yah, const unsigned int* __restrict__ yal,
        const unsigned int* __restrict__ xbh, const unsigned int* __restrict__ xbl,
        float* __restrict__ fxr, float* __restrict__ fxi){
    __shared__ float fyrl[16*260], fyil[16*260];
    int bwv = blockIdx.x;
    int tid = threadIdx.x;
    int wv = tid>>6, l = tid&63;

    for (int half=0; half<2; ++half){
        int nt = wv*2 + half;            // 0..15
        int x = nt*16 + (l&15);
        int klo = (l>>4)*8;
        const float* hp = h + bwv*NPLANE + x*256 + klo;
        f32x4 accR = {0.f,0.f,0.f,0.f}, accI = {0.f,0.f,0.f,0.f};
        for (int kt=0; kt<8; ++kt){
            float4 b0 = *reinterpret_cast<const float4*>(hp + kt*32);
            float4 b1 = *reinterpret_cast<const float4*>(hp + kt*32 + 4);
            float bv[8] = {b0.x,b0.y,b0.z,b0.w,b1.x,b1.y,b1.z,b1.w};
            bf16x8 bh, bl;
            #pragma unroll
            for (int e=0;e<8;e++){
                unsigned short hb = bf16_rne(bv[e]);
                bh[e] = (short)hb;
                bl[e] = (short)bf16_rne(bv[e] - bf16_tof(hb));
            }
            uint4 a0h = *reinterpret_cast<const uint4*>(&yah[(kt*64+l)*4]);
            uint4 a0l = *reinterpret_cast<const uint4*>(&yal[(kt*64+l)*4]);
            uint4 a1h = *reinterpret_cast<const uint4*>(&yah[(512 + kt*64 + l)*4]);
            uint4 a1l = *reinterpret_cast<const uint4*>(&yal[(512 + kt*64 + l)*4]);
            bf16x8 AH0 = __builtin_bit_cast(bf16x8, a0h);
            bf16x8 AL0 = __builtin_bit_cast(bf16x8, a0l);
            bf16x8 AH1 = __builtin_bit_cast(bf16x8, a1h);
            bf16x8 AL1 = __builtin_bit_cast(bf16x8, a1l);
            accR = __builtin_amdgcn_mfma_f32_16x16x32_bf16(AH0, bh, accR, 0,0,0);
            accR = __builtin_amdgcn_mfma_f32_16x16x32_bf16(AH0, bl, accR, 0,0,0);
            accR = __builtin_amdgcn_mfma_f32_16x16x32_bf16(AL0, bh, accR, 0,0,0);
            accI = __builtin_amdgcn_mfma_f32_16x16x32_bf16(AH1, bh, accI, 0,0,0);
            accI = __builtin_amdgcn_mfma_f32_16x16x32_bf16(AH1, bl, accI, 0,0,0);
            accI = __builtin_amdgcn_mfma_f32_16x16x32_bf16(AL1, bh, accI, 0,0,0);
        }
        int ky0 = (l>>4)*4;
        #pragma unroll
        for (int r=0;r<4;r++){
            fyrl[(ky0+r)*260 + x] = accR[r];
            fyil[(ky0+r)*260 + x] = accI[r];
        }
    }
    __syncthreads();

    if (wv < 2){
        int jh = wv;
        const float* ar = fyrl + (l&15)*260 + (l>>4)*8;
        const float* ai = fyil + (l&15)*260 + (l>>4)*8;
        f32x4 accR = {0.f,0.f,0.f,0.f}, accI = {0.f,0.f,0.f,0.f};
        for (int kt=0; kt<8; ++kt){
            float4 r0 = *reinterpret_cast<const float4*>(ar + kt*32);
            float4 r1 = *reinterpret_cast<const float4*>(ar + kt*32 + 4);
            float4 i0 = *reinterpret_cast<const float4*>(ai + kt*32);
            float4 i1 = *reinterpret_cast<const float4*>(ai + kt*32 + 4);
            float rv[8] = {r0.x,r0.y,r0.z,r0.w,r1.x,r1.y,r1.z,r1.w};
            float iv[8] = {i0.x,i0.y,i0.z,i0.w,i1.x,i1.y,i1.z,i1.w};
            bf16x8 Rh, Rl, Ih, Il;
            #pragma unroll
            for (int e=0;e<8;e++){
                unsigned short hb = bf16_rne(rv[e]);
                Rh[e] = (short)hb;
                Rl[e] = (short)bf16_rne(rv[e] - bf16_tof(hb));
                unsigned short hb2 = bf16_rne(iv[e]);
                Ih[e] = (short)hb2;
                Il[e] = (short)bf16_rne(iv[e] - bf16_tof(hb2));
            }
            int fb = (jh*512 + kt*64 + l)*4;   // tab stride = 1024 frags * 4
            uint4 ch = *reinterpret_cast<const uint4*>(&xbh[fb]);
            uint4 cl = *reinterpret_cast<const uint4*>(&xbl[fb]);
            uint4 sh = *reinterpret_cast<const uint4*>(&xbh[fb + 4096]);
            uint4 sl = *reinterpret_cast<const uint4*>(&xbl[fb + 4096]);
            uint4 ph = *reinterpret_cast<const uint4*>(&xbh[fb + 8192]);
            uint4 pl = *reinterpret_cast<const uint4*>(&xbl[fb + 8192]);
            bf16x8 CH = __builtin_bit_cast(bf16x8, ch);
            bf16x8 CL = __builtin_bit_cast(bf16x8, cl);
            bf16x8 SH = __builtin_bit_cast(bf16x8, sh);
            bf16x8 SL = __builtin_bit_cast(bf16x8, sl);
            bf16x8 PH = __builtin_bit_cast(bf16x8, ph);
            bf16x8 PL = __builtin_bit_cast(bf16x8, pl);
            accR = __builtin_amdgcn_mfma_f32_16x16x32_bf16(Rh, CH, accR, 0,0,0);
            accR = __builtin_amdgcn_mfma_f32_16x16x32_bf16(Rh, CL, accR, 0,0,0);
            accR = __builtin_amdgcn_mfma_f32_16x16x32_bf16(Rl, CH, accR, 0,0,0);
            accR = __builtin_amdgcn_mfma_f32_16x16x32_bf16(Ih, PH, accR, 0,0,0);
            accR = __builtin_amdgcn_mfma_f32_16x16x32_bf16(Ih, PL, accR, 0,0,0);
            accR = __builtin_amdgcn_mfma_f32_16x16x32_bf16(Il, PH, accR, 0,0,0);
            accI = __builtin_amdgcn_mfma_f32_16x16x32_bf16(Rh, SH, accI, 0,0,0);
            accI = __builtin_amdgcn_mfma_f32_16x16x32_bf16(Rh, SL, accI, 0,0,0);
            accI = __builtin_amdgcn_mfma_f32_16x16x32_bf16(Rl, SH, accI, 0,0,0);
            accI = __builtin_amdgcn_mfma_f32_16x16x32_bf16(Ih, CH, accI, 0,0,0);
            accI = __builtin_amdgcn_mfma_f32_16x16x32_bf16(Ih, CL, accI, 0,0,0);
            accI = __builtin_amdgcn_mfma_f32_16x16x32_bf16(Il, CH, accI, 0,0,0);
        }
        int ob = bwv*512 + jh*16 + (l&15);
        int ky0 = (l>>4)*4;
        #pragma unroll
        for (int r=0;r<4;r++){
            fxr[ob + (ky0+r)*32] = accR[r];
            fxi[ob + (ky0+r)*32] = accI[r];
        }
    }
}

// ---- complex mode mixing v2: coalesced repacked weights + mlp1, LDS writeout ----
// grid: 256 blocks = (b4, v2, ky16, jh2); 512 threads = (jg16, o32), o fastest.
__global__ void k_modemix(const float* __restrict__ fxr, const float* __restrict__ fxi,
                          const float* __restrict__ wpr, const float* __restrict__ wpi,
                          const float* __restrict__ m1, float* __restrict__ g2r, float* __restrict__ g2i){
    __shared__ float glr[32*17], gli[32*17], g2rl[32*17], g2il[32*17];
    int blk = blockIdx.x;
    int jh = blk&1, ky = (blk>>1)&15, v = (blk>>5)&1, b = blk>>6;
    int o = threadIdx.x&31, jg = threadIdx.x>>5;   // o fastest in lanes
    int j = jh*16 + jg;
    const float* wr = wpr + ((((v*16+ky)*32 + j)*32)<<5) + o;  // + i*32
    const float* wi = wpi + ((((v*16+ky)*32 + j)*32)<<5) + o;
    int fbase = (b*kW*kV + v)*512 + ky*32 + j;      // + i*1024 (broadcast across o)
    float re=0.f, im=0.f;
    #pragma unroll 8
    for (int i=0;i<32;i++){
        float fr=fxr[fbase+i*1024], fi=fxi[fbase+i*1024];
        float wrv=wr[i*32], wiv=wi[i*32];
        re += fr*wrv - fi*wiv;
        im += fr*wiv + fi*wrv;
    }
    glr[o*17+jg]=re; gli[o*17+jg]=im;
    __syncthreads();
    // mlp1: g2[o] = sum_i m1[o][i] * g[i]  (same-j mixing only)
    float r2=0.f, i2=0.f;
    #pragma unroll 8
    for (int i=0;i<32;i++){
        float m = m1[o*32+i];
        r2 += m*glr[i*17+jg];
        i2 += m*gli[i*17+jg];
    }
    g2rl[o*17+jg]=r2; g2il[o*17+jg]=i2;
    __syncthreads();
    // coalesced writeout: lanes j-fastest
    int o2 = threadIdx.x>>4, jl2 = threadIdx.x&15;
    int gid = ((b*kW + o2)*kV + v)*512 + ky*32 + jh*16 + jl2;
    g2r[gid] = g2rl[o2*17+jl2];
    g2i[gid] = g2il[o2*17+jl2];
}

// ---- FUSED inverse + pointwise, MFMA phase 2b ----
// grid: 2048 blocks = (b4, v2, xr256); 256 threads = 4 waves.
__global__ void k_invpoint(const float* __restrict__ g2r, const float* __restrict__ g2i,
                           const float* __restrict__ xic, const float* __restrict__ xis,
                           const float* __restrict__ iyc, const float* __restrict__ iys,
                           const float* __restrict__ b1,
                           const float* h, const float* res, float* out,
                           const unsigned int* __restrict__ m2h, const unsigned int* __restrict__ m2l,
                           const unsigned int* __restrict__ wwh, const unsigned int* __restrict__ wwl,
                           const float* __restrict__ b2,
                           const float* __restrict__ wb_, const float* __restrict__ bw_,
                           const float* __restrict__ bb_){
    __shared__ float frl[16*36], fil[16*36];   // [k][o] pad 36
    __shared__ float tl[32*260];               // [c][y] pad 260
    __shared__ float cinit[32], bwy_[32];
    int tid = threadIdx.x;
    int blk = blockIdx.x;
    int b = blk>>9, v = (blk>>8)&1, xr = blk&255;
    float gx = 9.5f + xr*(1.0f/255.0f);
    if (tid < 32){
        cinit[tid] = b2[tid] + wb_[tid] + bb_[tid] + bw_[tid*2]*gx;
        bwy_[tid] = bw_[tid*2+1];
    }

    // ---- phase 1: x-iDFT at fixed x=xr ----
    #pragma unroll
    for (int pp=0; pp<2; pp++){
        int p = tid + pp*256;
        int o = p>>4, k = p&15;
        const float* gr_ = g2r + (((b*kW + o)*kV + v)<<9) + k*32;
        const float* gi_ = g2i + (((b*kW + o)*kV + v)<<9) + k*32;
        float re=0.f, im=0.f;
        #pragma unroll 8
        for (int j=0;j<32;j++){
            float grv=gr_[j], giv=gi_[j];
            float c=xic[j*256+xr], s=xis[j*256+xr];
            re += grv*c - giv*s;
            im += grv*s + giv*c;
        }
        frl[k*36+o]=re; fil[k*36+o]=im;
    }
    __syncthreads();

    // ---- phase 2a: y-irfft, 4o x 8y tile; t = gelu(acc + b1) -> tl[c][y] ----
    {
        int og = tid&7, yg = tid>>3;
        int o0 = og*4, y0 = yg*8;
        float acc[4][8];
        #pragma unroll
        for (int oo=0;oo<4;oo++){
            float bb1 = b1[o0+oo];
            #pragma unroll
            for (int yy=0;yy<8;yy++) acc[oo][yy]=bb1;
        }
        #pragma unroll 4
        for (int k=0;k<16;k++){
            float4 yc0 = *reinterpret_cast<const float4*>(&iyc[k*256+y0]);
            float4 yc1 = *reinterpret_cast<const float4*>(&iyc[k*256+y0+4]);
            float4 ys0 = *reinterpret_cast<const float4*>(&iys[k*256+y0]);
            float4 ys1 = *reinterpret_cast<const float4*>(&iys[k*256+y0+4]);
            float4 fr4 = *reinterpret_cast<const float4*>(&frl[k*36+o0]);
            float4 fi4 = *reinterpret_cast<const float4*>(&fil[k*36+o0]);
            float frv[4]={fr4.x,fr4.y,fr4.z,fr4.w};
            float fiv[4]={fi4.x,fi4.y,fi4.z,fi4.w};
            #pragma unroll
            for (int oo=0;oo<4;oo++){
                acc[oo][0] += frv[oo]*yc0.x + fiv[oo]*ys0.x;
                acc[oo][1] += frv[oo]*yc0.y + fiv[oo]*ys0.y;
                acc[oo][2] += frv[oo]*yc0.z + fiv[oo]*ys0.z;
                acc[oo][3] += frv[oo]*yc0.w + fiv[oo]*ys0.w;
                acc[oo][4] += frv[oo]*yc1.x + fiv[oo]*ys1.x;
                acc[oo][5] += frv[oo]*yc1.y + fiv[oo]*ys1.y;
                acc[oo][6] += frv[oo]*yc1.z + fiv[oo]*ys1.z;
                acc[oo][7] += frv[oo]*yc1.w + fiv[oo]*ys1.w;
            }
        }
        #pragma unroll
        for (int oo=0;oo<4;oo++){
            float4 w0, w1;
            w0.x = gelu_f(acc[oo][0]); w0.y = gelu_f(acc[oo][1]);
            w0.z = gelu_f(acc[oo][2]); w0.w = gelu_f(acc[oo][3]);
            w1.x = gelu_f(acc[oo][4]); w1.y = gelu_f(acc[oo][5]);
            w1.z = gelu_f(acc[oo][6]); w1.w = gelu_f(acc[oo][7]);
            *reinterpret_cast<float4*>(&tl[(o0+oo)*260 + y0])   = w0;
            *reinterpret_cast<float4*>(&tl[(o0+oo)*260 + y0+4]) = w1;
        }
    }
    __syncthreads();

    // ---- phase 2b: MFMA mlp2(t) + ww(h) + base, gelu, +res ----
    int wv = tid>>6, l = tid&63;
    int lm = l&15, lg = l>>4;
    int pb = b*(kW*CHS) + v*NPLANE + xr*256;
    bf16x8 M2Hf[2], M2Lf[2], WWHf[2], WWLf[2];
    #pragma unroll
    for (int mt=0; mt<2; ++mt){
        M2Hf[mt] = __builtin_bit_cast(bf16x8, *reinterpret_cast<const uint4*>(&m2h[(mt*64+l)*4]));
        M2Lf[mt] = __builtin_bit_cast(bf16x8, *reinterpret_cast<const uint4*>(&m2l[(mt*64+l)*4]));
        WWHf[mt] = __builtin_bit_cast(bf16x8, *reinterpret_cast<const uint4*>(&wwh[(mt*64+l)*4]));
        WWLf[mt] = __builtin_bit_cast(bf16x8, *reinterpret_cast<const uint4*>(&wwl[(mt*64+l)*4]));
    }
    for (int nt=0; nt<4; ++nt){
        int y0 = wv*64 + nt*16;
        int yy = y0 + lm;
        float gyv = -0.5f + yy*(1.0f/255.0f);
        bf16x8 th, tlw, hh, hlw;
        #pragma unroll
        for (int e=0;e<8;e++){
            float tvv = tl[(lg*8+e)*260 + yy];
            unsigned short tb = bf16_rne(tvv);
            th[e] = (short)tb;
            tlw[e] = (short)bf16_rne(tvv - bf16_tof(tb));
            float hvv = h[pb + (lg*8+e)*CHS + yy];
            unsigned short hb = bf16_rne(hvv);
            hh[e] = (short)hb;
            hlw[e] = (short)bf16_rne(hvv - bf16_tof(hb));
        }
        for (int mt=0; mt<2; ++mt){
            f32x4 d = {0.f,0.f,0.f,0.f};
            d = __builtin_amdgcn_mfma_f32_16x16x32_bf16(M2Hf[mt], th,  d, 0,0,0);
            d = __builtin_amdgcn_mfma_f32_16x16x32_bf16(M2Hf[mt], tlw, d, 0,0,0);
            d = __builtin_amdgcn_mfma_f32_16x16x32_bf16(M2Lf[mt], th,  d, 0,0,0);
            d = __builtin_amdgcn_mfma_f32_16x16x32_bf16(WWHf[mt], hh,  d, 0,0,0);
            d = __builtin_amdgcn_mfma_f32_16x16x32_bf16(WWHf[mt], hlw, d, 0,0,0);
            d = __builtin_amdgcn_mfma_f32_16x16x32_bf16(WWLf[mt], hh,  d, 0,0,0);
            #pragma unroll
            for (int r=0;r<4;r++){
                int o = mt*16 + lg*4 + r;
                float val = gelu_f(d[r] + cinit[o] + bwy_[o]*gyv);
                int addr = pb + o*CHS + yy;
                if (res) val += res[addr];
                out[addr] = val;
            }
        }
    }
}

// ---- head via MFMA: LDS-staged h tile, fc1 (hi + weight-lo) + gelu + fc2 ----
// grid: 2048 blocks x 256 thr. RULE (3x: R7/R8/R14): MFMA bodies w/ fresh acc
// + loop-invariant A-frags must be FULLY unrolled w/ constant bounds.
__global__ __launch_bounds__(256) void k_head(const float* __restrict__ h,
        const unsigned int* __restrict__ whi, const unsigned int* __restrict__ wlo,
        const float* __restrict__ fc1b, const float* __restrict__ fc2w,
        const float* __restrict__ fc2b, float* __restrict__ out){
    __shared__ float hl[32*257];   // pad 257: all 64 lanes distinct banks (2-way = free)
    int tid = threadIdx.x;
    int plane = blockIdx.x>>8, xr = blockIdx.x&255;
    int b = plane>>1, v = plane&1;
    const float* hp = h + b*(kW*CHS) + v*NPLANE + xr*256;
    #pragma unroll 8
    for (int c=0;c<32;c++) hl[c*257 + tid] = hp[c*CHS + tid];  // coalesced 1KB/instr
    __syncthreads();

    int wv = tid>>6, l = tid&63;
    int lm = l&15, lg = l>>4;
    float f2b[5];
    #pragma unroll
    for (int j=0;j<5;j++) f2b[j] = fc2b[j];

    for (int mt=0; mt<4; ++mt){
        int pxl = wv*64 + mt*16 + lm;    // local pixel for A row
        bf16x8 ah;
        #pragma unroll
        for (int e=0;e<8;e++){
            float a = hl[(lg*8+e)*257 + pxl];
            ah[e] = (short)bf16_rne(a);
        }
        float fj[4][5];
        #pragma unroll
        for (int r=0;r<4;r++)
            #pragma unroll
            for (int j=0;j<5;j++) fj[r][j]=0.f;
        for (int q=0; q<4; ++q){
            #pragma unroll
            for (int ntq=0; ntq<4; ntq++){
                int nt = q*4 + ntq;
                uint4 rh = *reinterpret_cast<const uint4*>(&whi[(nt*64+l)*4]);
                uint4 rl = *reinterpret_cast<const uint4*>(&wlo[(nt*64+l)*4]);
                bf16x8 BH = __builtin_bit_cast(bf16x8, rh);
                bf16x8 BL = __builtin_bit_cast(bf16x8, rl);
                f32x4 d = {0.f,0.f,0.f,0.f};
                d = __builtin_amdgcn_mfma_f32_16x16x32_bf16(ah, BH, d, 0,0,0);
                d = __builtin_amdgcn_mfma_f32_16x16x32_bf16(ah, BL, d, 0,0,0);
                int o = nt*16 + lm;
                float b1  = fc1b[o];
                float w20 = fc2w[o*5+0], w21 = fc2w[o*5+1], w22 = fc2w[o*5+2];
                float w23 = fc2w[o*5+3], w24 = fc2w[o*5+4];
                #pragma unroll
                for (int r=0;r<4;r++){
                    float u = gelu_f(d[r] + b1);
                    fj[r][0] += u*w20; fj[r][1] += u*w21; fj[r][2] += u*w22;
                    fj[r][3] += u*w23; fj[r][4] += u*w24;
                }
            }
        }
        // reduce over the 16 o-lanes (lm bits)
        #pragma unroll
        for (int m=1; m<16; m<<=1){
            #pragma unroll
            for (int r=0;r<4;r++){
                #pragma unroll
                for (int j=0;j<5;j++) fj[r][j] += __shfl_xor(fj[r][j], m, 64);
            }
        }
        if (lm == 0){
            int prow = blockIdx.x*256 + wv*64 + mt*16 + lg*4;  // D rows m = lg*4+r
            #pragma unroll
            for (int r=0;r<4;r++){
                long ob = (long)(prow+r)*5;
                #pragma unroll
                for (int j=0;j<5;j++) out[ob+j] = fj[r][j] + f2b[j];
            }
        }
    }
}

extern "C" void kernel_launch(void* const* d_in, const int* in_sizes, int n_in,
                              void* d_out, int out_size, void* d_ws, size_t ws_size,
                              hipStream_t stream){
    const float* x    =(const float*)d_in[0];
    const float* fc0w =(const float*)d_in[1];
    const float* fc0b =(const float*)d_in[2];
    const float* w1r  =(const float*)d_in[3];
    const float* w1i  =(const float*)d_in[4];
    const float* w2r  =(const float*)d_in[5];
    const float* w2i  =(const float*)d_in[6];
    const float* m1w  =(const float*)d_in[7];
    const float* m1b  =(const float*)d_in[8];
    const float* m2w  =(const float*)d_in[9];
    const float* m2b  =(const float*)d_in[10];
    const float* ww   =(const float*)d_in[11];
    const float* wb   =(const float*)d_in[12];
    const float* bw   =(const float*)d_in[13];
    const float* bb   =(const float*)d_in[14];
    const float* fc1w =(const float*)d_in[15];
    const float* fc1b =(const float*)d_in[16];
    const float* fc2w =(const float*)d_in[17];
    const float* fc2b =(const float*)d_in[18];

    float* ws = (float*)d_ws;
    float* big[3] = {ws+OFF_BIG0, nullptr, ws+OFF_BIG2};
    float* fxr = ws+OFF_FXR; float* fxi = ws+OFF_FXI;
    float* gr  = ws+OFF_GR;  float* gi  = ws+OFF_GI;
    float* wpr = ws+OFF_WPR; float* wpi = ws+OFF_WPI;

    k_tables<<<32,256,0,stream>>>(ws, fc1w, m2w, ww);
    k_wpack<<<1536,256,0,stream>>>(w1r, w1i, w2r, w2i, wpr, wpi);
    k_fc0<<<2048,256,0,stream>>>(x, fc0w, fc0b, big[0]);

    // schedule: {in, out, res}
    const int s_in [6] = {0,0,2,2,2,0};
    const int s_out[6] = {0,2,2,2,0,0};
    const int s_res[6] = {-1,-1,0,-1,-1,2};

    for (int blk=0; blk<6; ++blk){
        float* in   = big[s_in[blk]];
        float* outb = big[s_out[blk]];
        const float* resp = (s_res[blk] < 0) ? nullptr : big[s_res[blk]];
        k_fwdfft<<<256,512,0,stream>>>(in,
            (const unsigned int*)(ws+OFF_YAH), (const unsigned int*)(ws+OFF_YAL),
            (const unsigned int*)(ws+OFF_XBH), (const unsigned int*)(ws+OFF_XBL),
            fxr, fxi);
        k_modemix<<<256,512,0,stream>>>(fxr, fxi,
            wpr + blk*1048576, wpi + blk*1048576,
            m1w+blk*1024, gr, gi);
        k_invpoint<<<2048,256,0,stream>>>(gr, gi, ws+OFF_TIC, ws+OFF_TIS,
            ws+OFF_IYC, ws+OFF_IYS, m1b+blk*32,
            in, resp, outb,
            (const unsigned int*)(ws+OFF_M2H) + blk*512,
            (const unsigned int*)(ws+OFF_M2L) + blk*512,
            (const unsigned int*)(ws+OFF_WWH) + blk*512,
            (const unsigned int*)(ws+OFF_WWL) + blk*512,
            m2b+blk*32, wb+blk*32, bw+blk*64, bb+blk*32);
    }
    k_head<<<2048,256,0,stream>>>(big[0],
        (const unsigned int*)(ws+OFF_WHI), (const unsigned int*)(ws+OFF_WLO),
        fc1b, fc2w, fc2b, (float*)d_out);
}